// Round 6
// baseline (1210.713 us; speedup 1.0000x reference)
//
#include <hip/hip_runtime.h>
#include <stdint.h>

#define NNODES 100000
#define NEDGES 600000
#define NGRAPH 2048
#define DD 128
#define NLAYER 5
#define NPAD 100096   // 782*128
#define SCAN_NB 391   // ceil(NNODES/256)

typedef __attribute__((ext_vector_type(8))) __bf16 bf16x8;
typedef __attribute__((ext_vector_type(4))) float f32x4;
typedef __attribute__((ext_vector_type(8))) ushort u16x8;

__device__ __forceinline__ ushort f2b(float f) {
    union { float f; uint32_t u; } v; v.f = f;
    uint32_t r = v.u + 0x7FFFu + ((v.u >> 16) & 1u);
    return (ushort)(r >> 16);
}

__device__ __forceinline__ float b2f(ushort u) {
    union { uint32_t u; float f; } v; v.u = ((uint32_t)u) << 16; return v.f;
}

__global__ void prep_w_kernel(const float* __restrict__ W1s, const float* __restrict__ W2s,
                              ushort* __restrict__ w1t, ushort* __restrict__ w2t) {
    int idx = blockIdx.x * 256 + threadIdx.x;
    const int per = 128 * 256;
    if (idx < NLAYER * per) {
        int i = idx / per, rem = idx % per;
        int n = rem >> 7, k = rem & 127;          // w1t[i][n(256)][k(128)] = W1s[i][k][n]
        w1t[idx] = f2b(W1s[(size_t)i * per + k * 256 + n]);
    } else if (idx < 2 * NLAYER * per) {
        int j = idx - NLAYER * per;
        int i = j / per, rem = j % per;
        int n = rem >> 8, k = rem & 255;          // w2t[i][n(128)][k(256)] = W2s[i][k][n]
        w2t[j] = f2b(W2s[(size_t)i * per + k * 128 + n]);
    }
}

__global__ void node_embed_kernel(const float* __restrict__ x, const float* __restrict__ W,
                                  const float* __restrict__ b, ushort* __restrict__ hb) {
    int idx = blockIdx.x * 256 + threadIdx.x;
    if (idx >= NNODES * 128) return;
    int n = idx >> 7, d = idx & 127;
    float v = b[d];
#pragma unroll
    for (int k = 0; k < 9; ++k) v += x[n * 9 + k] * W[k * 128 + d];
    hb[(size_t)n * 128 + d] = f2b(v);
}

__global__ void vn_init_kernel(const float* __restrict__ vne, float* __restrict__ vn) {
    int idx = blockIdx.x * 256 + threadIdx.x;
    if (idx >= NGRAPH * 128) return;
    vn[idx] = vne[idx & 127];
}

// ---------- CSR build (once per call; edges constant across layers) ----------

__global__ void deg_kernel(const int* __restrict__ dst, int* __restrict__ deg) {
    int e = blockIdx.x * 256 + threadIdx.x;
    if (e < NEDGES) atomicAdd(&deg[dst[e]], 1);
}

__global__ void scan_part_kernel(const int* __restrict__ deg, int* __restrict__ partials) {
    int i = blockIdx.x * 256 + threadIdx.x;
    int lane = threadIdx.x & 63, w = threadIdx.x >> 6;
    int v = (i < NNODES) ? deg[i] : 0;
#pragma unroll
    for (int o = 1; o < 64; o <<= 1) v += __shfl_xor(v, o);
    __shared__ int ws[4];
    if (lane == 0) ws[w] = v;
    __syncthreads();
    if (threadIdx.x == 0) partials[blockIdx.x] = ws[0] + ws[1] + ws[2] + ws[3];
}

__global__ __launch_bounds__(512)
void scan_top_kernel(int* __restrict__ partials) {
    __shared__ int s[512];
    int t = threadIdx.x;
    int v = (t < SCAN_NB) ? partials[t] : 0;
    s[t] = v;
    __syncthreads();
#pragma unroll
    for (int o = 1; o < 512; o <<= 1) {
        int n = (t >= o) ? s[t - o] : 0;
        __syncthreads();
        s[t] += n;
        __syncthreads();
    }
    if (t < SCAN_NB) partials[t] = s[t] - v;   // exclusive
}

__global__ void scan_blocks_kernel(const int* __restrict__ deg, const int* __restrict__ partials,
                                   int* __restrict__ rs, int* __restrict__ cursor) {
    int i = blockIdx.x * 256 + threadIdx.x;
    int lane = threadIdx.x & 63, w = threadIdx.x >> 6;
    int v = (i < NNODES) ? deg[i] : 0;
    int x = v;
#pragma unroll
    for (int o = 1; o < 64; o <<= 1) {
        int n = __shfl_up(x, o);
        if (lane >= o) x += n;
    }
    __shared__ int ws[4];
    if (lane == 63) ws[w] = x;
    __syncthreads();
    if (threadIdx.x == 0) {
        int a = 0;
#pragma unroll
        for (int k = 0; k < 4; ++k) { int t = ws[k]; ws[k] = a; a += t; }
    }
    __syncthreads();
    int excl = (x - v) + ws[w] + partials[blockIdx.x];
    if (i < NNODES) { rs[i] = excl; cursor[i] = excl; }
    if (i == 0) rs[NNODES] = NEDGES;
}

__global__ void csr_scatter_kernel(const int* __restrict__ src, const int* __restrict__ dst,
                                   int* __restrict__ cursor, int* __restrict__ csrc) {
    int e = blockIdx.x * 256 + threadIdx.x;
    if (e < NEDGES) {
        int p = atomicAdd(&cursor[dst[e]], 1);
        csrc[p] = src[e];
    }
}

__device__ __forceinline__ int lbound(const int* __restrict__ b, int key) {
    int lo = 0, hi = NNODES;
    while (lo < hi) { int m = (lo + hi) >> 1; if (b[m] < key) lo = m + 1; else hi = m; }
    return lo;
}

__global__ void gcnt_kernel(const int* __restrict__ batch, float* __restrict__ inv) {
    int g = blockIdx.x * 256 + threadIdx.x;
    if (g < NGRAPH) {
        int c = lbound(batch, g + 1) - lbound(batch, g);
        inv[g] = 1.f / (float)(c > 0 ? c : 1);
    }
}

// ---------- GIN aggregation: xb[i] = bf16( h[i] + sum_{j->i} h[j] ), h in bf16 ----------
// 16 nodes per 256-block; 16 lanes x 8 bf16 per row.
__global__ __launch_bounds__(256)
void gin_agg_kernel(const ushort* __restrict__ hb, const int* __restrict__ rs,
                    const int* __restrict__ csrc, ushort* __restrict__ xb) {
    int slot = threadIdx.x >> 4;
    int j = threadIdx.x & 15;
    int node = blockIdx.x * 16 + slot;
    if (node >= NNODES) return;
    int s = rs[node], e = rs[node + 1];
    u16x8 v0 = *(const u16x8*)(hb + (size_t)node * 128 + j * 8);
    float a[8];
#pragma unroll
    for (int t = 0; t < 8; ++t) a[t] = b2f(v0[t]);
    for (int k = s; k < e; ++k) {
        int sn = csrc[k];
        u16x8 v = *(const u16x8*)(hb + (size_t)sn * 128 + j * 8);
#pragma unroll
        for (int t = 0; t < 8; ++t) a[t] += b2f(v[t]);
    }
    u16x8 o;
#pragma unroll
    for (int t = 0; t < 8; ++t) o[t] = f2b(a[t]);
    *(u16x8*)(xb + (size_t)node * 128 + j * 8) = o;
}

// ---------- fused MLP: out = (relu(A@W1+b1))@W2 + b2 (bf16), + BN column stats ----------
__global__ __launch_bounds__(512)
void fused_mlp_kernel(const ushort* __restrict__ A, const ushort* __restrict__ W1,
                      const float* __restrict__ b1, const ushort* __restrict__ W2,
                      const float* __restrict__ b2, ushort* __restrict__ out_b,
                      float* __restrict__ stat_sum, float* __restrict__ stat_sq) {
    __shared__ __align__(16) ushort mid[32768];   // 64 KB, [g2][row][8] with XOR swizzle
    const int tid = threadIdx.x;
    const int lane = tid & 63, wid = tid >> 6;
    const int wm = wid >> 2, wn = wid & 3;        // 2 x 4 wave grid
    const int q = lane >> 4, l16 = lane & 15;
    const int rb = blockIdx.x * 128;

    f32x4 acc1[4][4] = {};
#pragma unroll
    for (int ks = 0; ks < 4; ++ks) {
        bf16x8 af[4], bw[4];
#pragma unroll
        for (int mi = 0; mi < 4; ++mi)
            af[mi] = *(const bf16x8*)(A + (size_t)(rb + wm * 64 + mi * 16 + l16) * 128 + ks * 32 + q * 8);
#pragma unroll
        for (int ni = 0; ni < 4; ++ni)
            bw[ni] = *(const bf16x8*)(W1 + (size_t)(wn * 64 + ni * 16 + l16) * 128 + ks * 32 + q * 8);
#pragma unroll
        for (int mi = 0; mi < 4; ++mi)
#pragma unroll
            for (int ni = 0; ni < 4; ++ni)
                acc1[mi][ni] = __builtin_amdgcn_mfma_f32_16x16x32_bf16(af[mi], bw[ni], acc1[mi][ni], 0, 0, 0);
    }

#pragma unroll
    for (int ni = 0; ni < 4; ++ni) {
        int col = wn * 64 + ni * 16 + l16;
        float bs = b1[col];
        int g2 = col >> 3, jj = col & 7;
#pragma unroll
        for (int mi = 0; mi < 4; ++mi) {
            int rowb = wm * 64 + mi * 16 + q * 4;
#pragma unroll
            for (int r = 0; r < 4; ++r) {
                int row = rowb + r;
                float v = acc1[mi][ni][r] + bs;
                v = v > 0.f ? v : 0.f;
                int idx = (g2 * 1024 + row * 8 + jj) ^ ((row & 12) << 2);
                mid[idx] = f2b(v);
            }
        }
    }
    __syncthreads();

    f32x4 acc2[4][2] = {};
#pragma unroll
    for (int ks = 0; ks < 8; ++ks) {
        bf16x8 af[4], bw[2];
#pragma unroll
        for (int mi = 0; mi < 4; ++mi) {
            int row = wm * 64 + mi * 16 + l16;
            int idx = ((ks * 4 + q) * 1024 + row * 8) ^ ((row & 12) << 2);
            af[mi] = *(const bf16x8*)&mid[idx];
        }
#pragma unroll
        for (int ni = 0; ni < 2; ++ni)
            bw[ni] = *(const bf16x8*)(W2 + (size_t)(wn * 32 + ni * 16 + l16) * 256 + ks * 32 + q * 8);
#pragma unroll
        for (int mi = 0; mi < 4; ++mi)
#pragma unroll
            for (int ni = 0; ni < 2; ++ni)
                acc2[mi][ni] = __builtin_amdgcn_mfma_f32_16x16x32_bf16(af[mi], bw[ni], acc2[mi][ni], 0, 0, 0);
    }

#pragma unroll
    for (int ni = 0; ni < 2; ++ni) {
        int col = wn * 32 + ni * 16 + l16;
        float bs = b2[col];
        float s = 0.f, sq = 0.f;
#pragma unroll
        for (int mi = 0; mi < 4; ++mi) {
            int row = rb + wm * 64 + mi * 16 + q * 4;
#pragma unroll
            for (int r = 0; r < 4; ++r) {
                float v = acc2[mi][ni][r] + bs;
                out_b[(size_t)(row + r) * 128 + col] = f2b(v);
                if (row + r < NNODES) { s += v; sq += v * v; }
            }
        }
        s  += __shfl_xor(s, 16);  s  += __shfl_xor(s, 32);
        sq += __shfl_xor(sq, 16); sq += __shfl_xor(sq, 32);
        if (lane < 16) {
            atomicAdd(&stat_sum[col], s);
            atomicAdd(&stat_sq[col], sq);
        }
    }
}

__global__ void bn_finalize_kernel(const float* __restrict__ sum, const float* __restrict__ sq,
                                   const float* __restrict__ g, const float* __restrict__ b,
                                   float* __restrict__ scale, float* __restrict__ shift) {
    int d = threadIdx.x;
    float mu = sum[d] * (1.f / NNODES);
    float var = sq[d] * (1.f / NNODES) - mu * mu;
    var = var < 0.f ? 0.f : var;
    float sc = g[d] * rsqrtf(var + 1e-5f);
    scale[d] = sc;
    shift[d] = b[d] - mu * sc;
}

// ---------- BN apply + residual + fused per-graph pool partials (h in bf16) ----------
// 512 thr: 32 groups x 16 lanes; 8 rows per group; 256 rows per block.
__global__ __launch_bounds__(512)
void bn_pool_apply_kernel(const ushort* __restrict__ m, const float* __restrict__ scale,
                          const float* __restrict__ shift, const int* __restrict__ batch,
                          ushort* __restrict__ hb, float* __restrict__ psum, int resid) {
    int j = threadIdx.x & 15, rgrp = threadIdx.x >> 4;
    int row0 = blockIdx.x * 256 + rgrp * 8;
    float sc[8], sh[8];
    {
        float4 a = ((const float4*)scale)[j * 2], b = ((const float4*)scale)[j * 2 + 1];
        sc[0]=a.x; sc[1]=a.y; sc[2]=a.z; sc[3]=a.w; sc[4]=b.x; sc[5]=b.y; sc[6]=b.z; sc[7]=b.w;
        float4 c = ((const float4*)shift)[j * 2], d = ((const float4*)shift)[j * 2 + 1];
        sh[0]=c.x; sh[1]=c.y; sh[2]=c.z; sh[3]=c.w; sh[4]=d.x; sh[5]=d.y; sh[6]=d.z; sh[7]=d.w;
    }
    float a[8];
#pragma unroll
    for (int t = 0; t < 8; ++t) a[t] = 0.f;
    int gcur = -1;
    for (int r = 0; r < 8; ++r) {
        int row = row0 + r;
        if (row >= NNODES) break;
        int g = batch[row];
        u16x8 mu = *(const u16x8*)(m + (size_t)row * 128 + j * 8);
        float w[8];
#pragma unroll
        for (int t = 0; t < 8; ++t) w[t] = fmaxf(b2f(mu[t]) * sc[t] + sh[t], 0.f);
        if (resid) {
            u16x8 hp = *(const u16x8*)(hb + (size_t)row * 128 + j * 8);
#pragma unroll
            for (int t = 0; t < 8; ++t) w[t] += b2f(hp[t]);
        }
        u16x8 o;
#pragma unroll
        for (int t = 0; t < 8; ++t) o[t] = f2b(w[t]);
        *(u16x8*)(hb + (size_t)row * 128 + j * 8) = o;
        if (g != gcur) {
            if (gcur >= 0) {
                float* p = psum + (size_t)gcur * 128 + j * 8;
#pragma unroll
                for (int t = 0; t < 8; ++t) atomicAdd(p + t, a[t]);
            }
            gcur = g;
#pragma unroll
            for (int t = 0; t < 8; ++t) a[t] = w[t];
        } else {
#pragma unroll
            for (int t = 0; t < 8; ++t) a[t] += w[t];
        }
    }
    if (gcur >= 0) {
        float* p = psum + (size_t)gcur * 128 + j * 8;
#pragma unroll
        for (int t = 0; t < 8; ++t) atomicAdd(p + t, a[t]);
    }
}

__global__ void vn_update_kernel(const float* __restrict__ psum, const float* __restrict__ inv,
                                 const float* __restrict__ W1, const float* __restrict__ b1,
                                 const float* __restrict__ W2, const float* __restrict__ b2,
                                 float* __restrict__ vn) {
    __shared__ float t[128], t1[128];
    int g = blockIdx.x, d = threadIdx.x;
    t[d] = psum[g * 128 + d] * inv[g];
    __syncthreads();
    float a = b1[d];
    for (int k = 0; k < 128; ++k) a += t[k] * W1[k * 128 + d];
    t1[d] = fmaxf(a, 0.f);
    __syncthreads();
    float o = b2[d];
    for (int k = 0; k < 128; ++k) o += t1[k] * W2[k * 128 + d];
    vn[g * 128 + d] += o;
}

// ---------- h += vn[batch]; FINAL: write f32 outN + per-graph pool partials ----------
template<int FINAL>
__global__ __launch_bounds__(512)
void add_vn_kernel(ushort* __restrict__ hb, const float* __restrict__ vn,
                   const int* __restrict__ batch, float* __restrict__ outN,
                   float* __restrict__ psum) {
    int j = threadIdx.x & 15, rgrp = threadIdx.x >> 4;
    int row0 = blockIdx.x * 256 + rgrp * 8;
    float a[8];
#pragma unroll
    for (int t = 0; t < 8; ++t) a[t] = 0.f;
    int gcur = -1;
    for (int r = 0; r < 8; ++r) {
        int row = row0 + r;
        if (row >= NNODES) break;
        int g = batch[row];
        float vg[8];
        {
            float4 v0 = ((const float4*)(vn + (size_t)g * 128))[j * 2];
            float4 v1 = ((const float4*)(vn + (size_t)g * 128))[j * 2 + 1];
            vg[0]=v0.x; vg[1]=v0.y; vg[2]=v0.z; vg[3]=v0.w;
            vg[4]=v1.x; vg[5]=v1.y; vg[6]=v1.z; vg[7]=v1.w;
        }
        u16x8 hv = *(const u16x8*)(hb + (size_t)row * 128 + j * 8);
        float w[8];
#pragma unroll
        for (int t = 0; t < 8; ++t) w[t] = b2f(hv[t]) + vg[t];
        if (FINAL) {
            float4* op = (float4*)(outN + (size_t)row * 128 + j * 8);
            op[0] = make_float4(w[0], w[1], w[2], w[3]);
            op[1] = make_float4(w[4], w[5], w[6], w[7]);
            if (g != gcur) {
                if (gcur >= 0) {
                    float* p = psum + (size_t)gcur * 128 + j * 8;
#pragma unroll
                    for (int t = 0; t < 8; ++t) atomicAdd(p + t, a[t]);
                }
                gcur = g;
#pragma unroll
                for (int t = 0; t < 8; ++t) a[t] = w[t];
            } else {
#pragma unroll
                for (int t = 0; t < 8; ++t) a[t] += w[t];
            }
        } else {
            u16x8 o;
#pragma unroll
            for (int t = 0; t < 8; ++t) o[t] = f2b(w[t]);
            *(u16x8*)(hb + (size_t)row * 128 + j * 8) = o;
        }
    }
    if (FINAL && gcur >= 0) {
        float* p = psum + (size_t)gcur * 128 + j * 8;
#pragma unroll
        for (int t = 0; t < 8; ++t) atomicAdd(p + t, a[t]);
    }
}

__global__ void graph_mlp_kernel(const float* __restrict__ psum, const float* __restrict__ inv,
                                 const float* __restrict__ W1, const float* __restrict__ b1,
                                 const float* __restrict__ lng, const float* __restrict__ lnb,
                                 const float* __restrict__ W2, const float* __restrict__ b2,
                                 float* __restrict__ out) {
    __shared__ float t[128], t1[128], red[2];
    int g = blockIdx.x, d = threadIdx.x;
    int lane = d & 63, w = d >> 6;
    t[d] = psum[g * 128 + d] * inv[g];
    __syncthreads();
    float a = b1[d];
    for (int k = 0; k < 128; ++k) a += t[k] * W1[k * 128 + d];
    float s = a;
#pragma unroll
    for (int o = 1; o < 64; o <<= 1) s += __shfl_xor(s, o);
    if (lane == 0) red[w] = s;
    __syncthreads();
    float mu = (red[0] + red[1]) * (1.f / 128.f);
    float dv = a - mu;
    float qq = dv * dv;
#pragma unroll
    for (int o = 1; o < 64; o <<= 1) qq += __shfl_xor(qq, o);
    __syncthreads();
    if (lane == 0) red[w] = qq;
    __syncthreads();
    float var = (red[0] + red[1]) * (1.f / 128.f);
    float v = dv * rsqrtf(var + 1e-5f) * lng[d] + lnb[d];
    v = fmaxf(v, 0.f);
    t1[d] = v;
    __syncthreads();
    float o2 = b2[d];
    for (int k = 0; k < 128; ++k) o2 += t1[k] * W2[k * 128 + d];
    out[g * 128 + d] = o2;
}

extern "C" void kernel_launch(void* const* d_in, const int* in_sizes, int n_in,
                              void* d_out, int out_size, void* d_ws, size_t ws_size,
                              hipStream_t stream) {
    const float* x    = (const float*)d_in[0];
    const int*   edge = (const int*)d_in[1];
    const int*   src  = edge;
    const int*   dst  = edge + NEDGES;
    const int*   batch = (const int*)d_in[2];
    const float* nW   = (const float*)d_in[3];
    const float* nb   = (const float*)d_in[4];
    const float* W1s  = (const float*)d_in[5];
    const float* b1s  = (const float*)d_in[6];
    const float* W2s  = (const float*)d_in[7];
    const float* b2s  = (const float*)d_in[8];
    const float* bng  = (const float*)d_in[9];
    const float* bnb  = (const float*)d_in[10];
    const float* vne  = (const float*)d_in[11];
    const float* vW1  = (const float*)d_in[12];
    const float* vb1  = (const float*)d_in[13];
    const float* vW2  = (const float*)d_in[14];
    const float* vb2  = (const float*)d_in[15];
    const float* gW1  = (const float*)d_in[16];
    const float* gb1  = (const float*)d_in[17];
    const float* lng  = (const float*)d_in[18];
    const float* lnb  = (const float*)d_in[19];
    const float* gW2  = (const float*)d_in[20];
    const float* gb2  = (const float*)d_in[21];

    char* ws = (char*)d_ws;
    auto alloc = [&](size_t bytes) { char* p = ws; ws += (bytes + 255) & ~(size_t)255; return p; };
    float*  stats = (float*)alloc(256 * 4);                    // colsum+colsq, adjacent to tmp
    float*  tmp   = (float*)alloc((size_t)NGRAPH * 128 * 4);   // per-layer pool partials
    float*  tmp2  = (float*)alloc((size_t)NGRAPH * 128 * 4);   // final pool partials
    ushort* hb    = (ushort*)alloc((size_t)NPAD * 128 * 2);    // h in bf16
    ushort* mbuf  = (ushort*)alloc((size_t)NPAD * 128 * 2);
    ushort* xb    = (ushort*)alloc((size_t)NPAD * 128 * 2);
    float*  vn    = (float*)alloc((size_t)NGRAPH * 128 * 4);
    ushort* w1t   = (ushort*)alloc((size_t)NLAYER * 256 * 128 * 2);
    ushort* w2t   = (ushort*)alloc((size_t)NLAYER * 128 * 256 * 2);
    float*  scale = (float*)alloc(128 * 4);
    float*  shift = (float*)alloc(128 * 4);
    float*  inv   = (float*)alloc((size_t)NGRAPH * 4);
    int*    deg   = (int*)alloc((size_t)NNODES * 4);
    int*    rs    = (int*)alloc((size_t)(NNODES + 1) * 4);
    int*    cursor= (int*)alloc((size_t)NNODES * 4);
    int*    csrc  = (int*)alloc((size_t)NEDGES * 4);
    int*    partials = (int*)alloc((size_t)SCAN_NB * 4);
    float*  colsum = stats;
    float*  colsq  = stats + 128;

    float* outN = (float*)d_out;
    float* outG = outN + (size_t)NNODES * 128;

    // CSR build (edges constant across layers)
    hipMemsetAsync(deg, 0, (size_t)NNODES * 4, stream);
    hipMemsetAsync(tmp2, 0, (size_t)NGRAPH * 128 * 4, stream);
    deg_kernel<<<(NEDGES + 255) / 256, 256, 0, stream>>>(dst, deg);
    scan_part_kernel<<<SCAN_NB, 256, 0, stream>>>(deg, partials);
    scan_top_kernel<<<1, 512, 0, stream>>>(partials);
    scan_blocks_kernel<<<SCAN_NB, 256, 0, stream>>>(deg, partials, rs, cursor);
    csr_scatter_kernel<<<(NEDGES + 255) / 256, 256, 0, stream>>>(src, dst, cursor, csrc);
    gcnt_kernel<<<(NGRAPH + 255) / 256, 256, 0, stream>>>(batch, inv);

    prep_w_kernel<<<(2 * NLAYER * 128 * 256 + 255) / 256, 256, 0, stream>>>(W1s, W2s, w1t, w2t);
    node_embed_kernel<<<(NNODES * 128 + 255) / 256, 256, 0, stream>>>(x, nW, nb, hb);
    vn_init_kernel<<<(NGRAPH * 128 + 255) / 256, 256, 0, stream>>>(vne, vn);

    for (int i = 0; i < NLAYER; ++i) {
        hipMemsetAsync(stats, 0, 1024 + (size_t)NGRAPH * 128 * 4, stream);  // stats + tmp
        gin_agg_kernel<<<(NNODES + 15) / 16, 256, 0, stream>>>(hb, rs, csrc, xb);
        fused_mlp_kernel<<<NPAD / 128, 512, 0, stream>>>(
            xb, w1t + (size_t)i * 256 * 128, b1s + i * 256,
            w2t + (size_t)i * 128 * 256, b2s + i * 128, mbuf, colsum, colsq);
        bn_finalize_kernel<<<1, 128, 0, stream>>>(colsum, colsq, bng + i * 128, bnb + i * 128, scale, shift);
        bn_pool_apply_kernel<<<(NNODES + 255) / 256, 512, 0, stream>>>(
            mbuf, scale, shift, batch, hb, tmp, i > 0 ? 1 : 0);
        vn_update_kernel<<<NGRAPH, 128, 0, stream>>>(tmp, inv, vW1, vb1, vW2, vb2, vn);
        if (i < NLAYER - 1)
            add_vn_kernel<0><<<(NNODES + 255) / 256, 512, 0, stream>>>(hb, vn, batch, nullptr, nullptr);
        else
            add_vn_kernel<1><<<(NNODES + 255) / 256, 512, 0, stream>>>(hb, vn, batch, outN, tmp2);
    }
    graph_mlp_kernel<<<NGRAPH, 128, 0, stream>>>(tmp2, inv, gW1, gb1, lng, lnb, gW2, gb2, outG);
}

// Round 7
// 1119.316 us; speedup vs baseline: 1.0817x; 1.0817x over previous
//
#include <hip/hip_runtime.h>
#include <stdint.h>

#define NNODES 100000
#define NEDGES 600000
#define NGRAPH 2048
#define DD 128
#define NLAYER 5
#define NPAD 100096   // 782*128 = 1564*64
#define SCAN_NB 391   // ceil(NNODES/256)

typedef __attribute__((ext_vector_type(8))) __bf16 bf16x8;
typedef __attribute__((ext_vector_type(4))) float f32x4;
typedef __attribute__((ext_vector_type(8))) ushort u16x8;

__device__ __forceinline__ ushort f2b(float f) {
    union { float f; uint32_t u; } v; v.f = f;
    uint32_t r = v.u + 0x7FFFu + ((v.u >> 16) & 1u);
    return (ushort)(r >> 16);
}

__device__ __forceinline__ float b2f(ushort u) {
    union { uint32_t u; float f; } v; v.u = ((uint32_t)u) << 16; return v.f;
}

__device__ __forceinline__ void gload_lds16(const void* g, void* l) {
    __builtin_amdgcn_global_load_lds(
        (const __attribute__((address_space(1))) void*)g,
        (__attribute__((address_space(3))) void*)l, 16, 0, 0);
}

__global__ void prep_w_kernel(const float* __restrict__ W1s, const float* __restrict__ W2s,
                              ushort* __restrict__ w1t, ushort* __restrict__ w2t) {
    int idx = blockIdx.x * 256 + threadIdx.x;
    const int per = 128 * 256;
    if (idx < NLAYER * per) {
        int i = idx / per, rem = idx % per;
        int n = rem >> 7, k = rem & 127;          // w1t[i][n(256)][k(128)] = W1s[i][k][n]
        w1t[idx] = f2b(W1s[(size_t)i * per + k * 256 + n]);
    } else if (idx < 2 * NLAYER * per) {
        int j = idx - NLAYER * per;
        int i = j / per, rem = j % per;
        int n = rem >> 8, k = rem & 255;          // w2t[i][n(128)][k(256)] = W2s[i][k][n]
        w2t[j] = f2b(W2s[(size_t)i * per + k * 128 + n]);
    }
}

__global__ void node_embed_kernel(const float* __restrict__ x, const float* __restrict__ W,
                                  const float* __restrict__ b, ushort* __restrict__ hb) {
    int idx = blockIdx.x * 256 + threadIdx.x;
    if (idx >= NNODES * 128) return;
    int n = idx >> 7, d = idx & 127;
    float v = b[d];
#pragma unroll
    for (int k = 0; k < 9; ++k) v += x[n * 9 + k] * W[k * 128 + d];
    hb[(size_t)n * 128 + d] = f2b(v);
}

__global__ void vn_init_kernel(const float* __restrict__ vne, float* __restrict__ vn) {
    int idx = blockIdx.x * 256 + threadIdx.x;
    if (idx >= NGRAPH * 128) return;
    vn[idx] = vne[idx & 127];
}

// ---------- CSR build (once per call; edges constant across layers) ----------

__global__ void deg_kernel(const int* __restrict__ dst, int* __restrict__ deg) {
    int e = blockIdx.x * 256 + threadIdx.x;
    if (e < NEDGES) atomicAdd(&deg[dst[e]], 1);
}

__global__ void scan_part_kernel(const int* __restrict__ deg, int* __restrict__ partials) {
    int i = blockIdx.x * 256 + threadIdx.x;
    int lane = threadIdx.x & 63, w = threadIdx.x >> 6;
    int v = (i < NNODES) ? deg[i] : 0;
#pragma unroll
    for (int o = 1; o < 64; o <<= 1) v += __shfl_xor(v, o);
    __shared__ int ws[4];
    if (lane == 0) ws[w] = v;
    __syncthreads();
    if (threadIdx.x == 0) partials[blockIdx.x] = ws[0] + ws[1] + ws[2] + ws[3];
}

__global__ __launch_bounds__(512)
void scan_top_kernel(int* __restrict__ partials) {
    __shared__ int s[512];
    int t = threadIdx.x;
    int v = (t < SCAN_NB) ? partials[t] : 0;
    s[t] = v;
    __syncthreads();
#pragma unroll
    for (int o = 1; o < 512; o <<= 1) {
        int n = (t >= o) ? s[t - o] : 0;
        __syncthreads();
        s[t] += n;
        __syncthreads();
    }
    if (t < SCAN_NB) partials[t] = s[t] - v;   // exclusive
}

__global__ void scan_blocks_kernel(const int* __restrict__ deg, const int* __restrict__ partials,
                                   int* __restrict__ rs, int* __restrict__ cursor) {
    int i = blockIdx.x * 256 + threadIdx.x;
    int lane = threadIdx.x & 63, w = threadIdx.x >> 6;
    int v = (i < NNODES) ? deg[i] : 0;
    int x = v;
#pragma unroll
    for (int o = 1; o < 64; o <<= 1) {
        int n = __shfl_up(x, o);
        if (lane >= o) x += n;
    }
    __shared__ int ws[4];
    if (lane == 63) ws[w] = x;
    __syncthreads();
    if (threadIdx.x == 0) {
        int a = 0;
#pragma unroll
        for (int k = 0; k < 4; ++k) { int t = ws[k]; ws[k] = a; a += t; }
    }
    __syncthreads();
    int excl = (x - v) + ws[w] + partials[blockIdx.x];
    if (i < NNODES) { rs[i] = excl; cursor[i] = excl; }
    if (i == 0) rs[NNODES] = NEDGES;
}

__global__ void csr_scatter_kernel(const int* __restrict__ src, const int* __restrict__ dst,
                                   int* __restrict__ cursor, int* __restrict__ csrc) {
    int e = blockIdx.x * 256 + threadIdx.x;
    if (e < NEDGES) {
        int p = atomicAdd(&cursor[dst[e]], 1);
        csrc[p] = src[e];
    }
}

__device__ __forceinline__ int lbound(const int* __restrict__ b, int key) {
    int lo = 0, hi = NNODES;
    while (lo < hi) { int m = (lo + hi) >> 1; if (b[m] < key) lo = m + 1; else hi = m; }
    return lo;
}

__global__ void gcnt_kernel(const int* __restrict__ batch, float* __restrict__ inv) {
    int g = blockIdx.x * 256 + threadIdx.x;
    if (g < NGRAPH) {
        int c = lbound(batch, g + 1) - lbound(batch, g);
        inv[g] = 1.f / (float)(c > 0 ? c : 1);
    }
}

// ---------- GIN aggregation: xb[i] = bf16( h[i] + sum_{j->i} h[j] ), h in bf16 ----------

__global__ __launch_bounds__(256)
void gin_agg_kernel(const ushort* __restrict__ hb, const int* __restrict__ rs,
                    const int* __restrict__ csrc, ushort* __restrict__ xb) {
    int slot = threadIdx.x >> 4;
    int j = threadIdx.x & 15;
    int node = blockIdx.x * 16 + slot;
    if (node >= NNODES) return;
    int s = rs[node], e = rs[node + 1];
    u16x8 v0 = *(const u16x8*)(hb + (size_t)node * 128 + j * 8);
    float a[8];
#pragma unroll
    for (int t = 0; t < 8; ++t) a[t] = b2f(v0[t]);
    for (int k = s; k < e; ++k) {
        int sn = csrc[k];
        u16x8 v = *(const u16x8*)(hb + (size_t)sn * 128 + j * 8);
#pragma unroll
        for (int t = 0; t < 8; ++t) a[t] += b2f(v[t]);
    }
    u16x8 o;
#pragma unroll
    for (int t = 0; t < 8; ++t) o[t] = f2b(a[t]);
    *(u16x8*)(xb + (size_t)node * 128 + j * 8) = o;
}

// ---------- fused MLP v3: 64-row tile, 4 waves, async A staging, 3 blocks/CU ----------
// A: [NPAD][128] bf16. W1: [256][128]. W2: [128][256]. out_b: [NPAD][128] bf16.
__global__ __launch_bounds__(256)
void fused_mlp_kernel(const ushort* __restrict__ A, const ushort* __restrict__ W1,
                      const float* __restrict__ b1, const ushort* __restrict__ W2,
                      const float* __restrict__ b2, ushort* __restrict__ out_b,
                      float* __restrict__ stat_sum, float* __restrict__ stat_sq) {
    __shared__ __align__(16) ushort lA[8192];     // 16KB: [ks:4][q:4][row:64][8]
    __shared__ __align__(16) ushort mid[16384];   // 32KB: [g2:32][row:64][8]
    const int tid = threadIdx.x;
    const int lane = tid & 63, w = tid >> 6;      // 4 waves; w = phase-1 n-quadrant
    const int q = lane >> 4, l16 = lane & 15;
    const int rb = blockIdx.x * 64;

    // stage A tile: lane order == linear LDS; source permuted so LDS = [ks][q][row][8]
    // chunk c = p*256 + w*64 + lane  ->  (ks,qq,row) = (p, w, lane)
#pragma unroll
    for (int p = 0; p < 4; ++p) {
        const ushort* gsrc = A + (size_t)(rb + lane) * 128 + p * 32 + w * 8;
        gload_lds16(gsrc, &lA[(size_t)(p * 256 + w * 64 + lane) * 8]);
    }
    __syncthreads();

    // ---- phase 1: C1[64][256] = A@W1; wave w owns cols w*64..w*64+63 ----
    f32x4 acc1[4][4] = {};
#pragma unroll
    for (int ks = 0; ks < 4; ++ks) {
        bf16x8 af[4], bw[4];
#pragma unroll
        for (int mi = 0; mi < 4; ++mi)
            af[mi] = *(const bf16x8*)&lA[ks * 2048 + q * 512 + (mi * 16 + l16) * 8];
#pragma unroll
        for (int ni = 0; ni < 4; ++ni)
            bw[ni] = *(const bf16x8*)(W1 + (size_t)(w * 64 + ni * 16 + l16) * 128 + ks * 32 + q * 8);
#pragma unroll
        for (int mi = 0; mi < 4; ++mi)
#pragma unroll
            for (int ni = 0; ni < 4; ++ni)
                acc1[mi][ni] = __builtin_amdgcn_mfma_f32_16x16x32_bf16(af[mi], bw[ni], acc1[mi][ni], 0, 0, 0);
    }

    // relu(C1+b1) -> bf16 -> mid [g2][row][8]
#pragma unroll
    for (int ni = 0; ni < 4; ++ni) {
        int col = w * 64 + ni * 16 + l16;         // phase-2 k index
        float bs = b1[col];
        int g2 = col >> 3, jj = col & 7;
#pragma unroll
        for (int mi = 0; mi < 4; ++mi) {
            int rowb = mi * 16 + q * 4;
#pragma unroll
            for (int r = 0; r < 4; ++r) {
                float v = acc1[mi][ni][r] + bs;
                v = v > 0.f ? v : 0.f;
                mid[g2 * 512 + (rowb + r) * 8 + jj] = f2b(v);
            }
        }
    }
    __syncthreads();

    // ---- phase 2: C2[64][128] = mid@W2 + b2; wave w owns cols w*32..w*32+31 ----
    f32x4 acc2[4][2] = {};
#pragma unroll
    for (int ks = 0; ks < 8; ++ks) {
        bf16x8 af[4], bw[2];
#pragma unroll
        for (int mi = 0; mi < 4; ++mi)
            af[mi] = *(const bf16x8*)&mid[(ks * 4 + q) * 512 + (mi * 16 + l16) * 8];
#pragma unroll
        for (int ni = 0; ni < 2; ++ni)
            bw[ni] = *(const bf16x8*)(W2 + (size_t)(w * 32 + ni * 16 + l16) * 256 + ks * 32 + q * 8);
#pragma unroll
        for (int mi = 0; mi < 4; ++mi)
#pragma unroll
            for (int ni = 0; ni < 2; ++ni)
                acc2[mi][ni] = __builtin_amdgcn_mfma_f32_16x16x32_bf16(af[mi], bw[ni], acc2[mi][ni], 0, 0, 0);
    }

#pragma unroll
    for (int ni = 0; ni < 2; ++ni) {
        int col = w * 32 + ni * 16 + l16;
        float bs = b2[col];
        float s = 0.f, sq = 0.f;
#pragma unroll
        for (int mi = 0; mi < 4; ++mi) {
            int row = rb + mi * 16 + q * 4;
#pragma unroll
            for (int r = 0; r < 4; ++r) {
                float v = acc2[mi][ni][r] + bs;
                out_b[(size_t)(row + r) * 128 + col] = f2b(v);
                if (row + r < NNODES) { s += v; sq += v * v; }
            }
        }
        s  += __shfl_xor(s, 16);  s  += __shfl_xor(s, 32);
        sq += __shfl_xor(sq, 16); sq += __shfl_xor(sq, 32);
        if (lane < 16) {
            atomicAdd(&stat_sum[col], s);
            atomicAdd(&stat_sq[col], sq);
        }
    }
}

// ---------- BN finalize (per-block) + apply + residual + per-graph pool partials ----------
__global__ __launch_bounds__(512)
void bn_pool_apply_kernel(const ushort* __restrict__ m, const float* __restrict__ colsum,
                          const float* __restrict__ colsq, const float* __restrict__ bng,
                          const float* __restrict__ bnb, const int* __restrict__ batch,
                          ushort* __restrict__ hb, float* __restrict__ psum, int resid) {
    __shared__ float sC[128], sS[128];
    if (threadIdx.x < 128) {
        int d = threadIdx.x;
        float mu = colsum[d] * (1.f / NNODES);
        float var = colsq[d] * (1.f / NNODES) - mu * mu;
        var = var < 0.f ? 0.f : var;
        float sc = bng[d] * rsqrtf(var + 1e-5f);
        sC[d] = sc;
        sS[d] = bnb[d] - mu * sc;
    }
    __syncthreads();
    int j = threadIdx.x & 15, rgrp = threadIdx.x >> 4;
    int row0 = blockIdx.x * 256 + rgrp * 8;
    float sc[8], sh[8];
#pragma unroll
    for (int t = 0; t < 8; ++t) { sc[t] = sC[j * 8 + t]; sh[t] = sS[j * 8 + t]; }
    float a[8];
#pragma unroll
    for (int t = 0; t < 8; ++t) a[t] = 0.f;
    int gcur = -1;
    for (int r = 0; r < 8; ++r) {
        int row = row0 + r;
        if (row >= NNODES) break;
        int g = batch[row];
        u16x8 mu = *(const u16x8*)(m + (size_t)row * 128 + j * 8);
        float wv[8];
#pragma unroll
        for (int t = 0; t < 8; ++t) wv[t] = fmaxf(b2f(mu[t]) * sc[t] + sh[t], 0.f);
        if (resid) {
            u16x8 hp = *(const u16x8*)(hb + (size_t)row * 128 + j * 8);
#pragma unroll
            for (int t = 0; t < 8; ++t) wv[t] += b2f(hp[t]);
        }
        u16x8 o;
#pragma unroll
        for (int t = 0; t < 8; ++t) o[t] = f2b(wv[t]);
        *(u16x8*)(hb + (size_t)row * 128 + j * 8) = o;
        if (g != gcur) {
            if (gcur >= 0) {
                float* p = psum + (size_t)gcur * 128 + j * 8;
#pragma unroll
                for (int t = 0; t < 8; ++t) atomicAdd(p + t, a[t]);
            }
            gcur = g;
#pragma unroll
            for (int t = 0; t < 8; ++t) a[t] = wv[t];
        } else {
#pragma unroll
            for (int t = 0; t < 8; ++t) a[t] += wv[t];
        }
    }
    if (gcur >= 0) {
        float* p = psum + (size_t)gcur * 128 + j * 8;
#pragma unroll
        for (int t = 0; t < 8; ++t) atomicAdd(p + t, a[t]);
    }
}

// vn update; also zeroes psum and stats for the next layer (determinism: memset once upfront)
__global__ void vn_update_kernel(float* __restrict__ psum, const float* __restrict__ inv,
                                 const float* __restrict__ W1, const float* __restrict__ b1,
                                 const float* __restrict__ W2, const float* __restrict__ b2,
                                 float* __restrict__ vn, float* __restrict__ stats) {
    __shared__ float t[128], t1[128];
    int g = blockIdx.x, d = threadIdx.x;
    t[d] = psum[g * 128 + d] * inv[g];
    psum[g * 128 + d] = 0.f;
    if (g == 0) { stats[d] = 0.f; stats[128 + d] = 0.f; }
    __syncthreads();
    float a = b1[d];
    for (int k = 0; k < 128; ++k) a += t[k] * W1[k * 128 + d];
    t1[d] = fmaxf(a, 0.f);
    __syncthreads();
    float o = b2[d];
    for (int k = 0; k < 128; ++k) o += t1[k] * W2[k * 128 + d];
    vn[g * 128 + d] += o;
}

// ---------- h += vn[batch]; FINAL: write f32 outN + per-graph pool partials ----------
template<int FINAL>
__global__ __launch_bounds__(512)
void add_vn_kernel(ushort* __restrict__ hb, const float* __restrict__ vn,
                   const int* __restrict__ batch, float* __restrict__ outN,
                   float* __restrict__ psum) {
    int j = threadIdx.x & 15, rgrp = threadIdx.x >> 4;
    int row0 = blockIdx.x * 256 + rgrp * 8;
    float a[8];
#pragma unroll
    for (int t = 0; t < 8; ++t) a[t] = 0.f;
    int gcur = -1;
    for (int r = 0; r < 8; ++r) {
        int row = row0 + r;
        if (row >= NNODES) break;
        int g = batch[row];
        float vg[8];
        {
            float4 v0 = ((const float4*)(vn + (size_t)g * 128))[j * 2];
            float4 v1 = ((const float4*)(vn + (size_t)g * 128))[j * 2 + 1];
            vg[0]=v0.x; vg[1]=v0.y; vg[2]=v0.z; vg[3]=v0.w;
            vg[4]=v1.x; vg[5]=v1.y; vg[6]=v1.z; vg[7]=v1.w;
        }
        u16x8 hv = *(const u16x8*)(hb + (size_t)row * 128 + j * 8);
        float wv[8];
#pragma unroll
        for (int t = 0; t < 8; ++t) wv[t] = b2f(hv[t]) + vg[t];
        if (FINAL) {
            float4* op = (float4*)(outN + (size_t)row * 128 + j * 8);
            op[0] = make_float4(wv[0], wv[1], wv[2], wv[3]);
            op[1] = make_float4(wv[4], wv[5], wv[6], wv[7]);
            if (g != gcur) {
                if (gcur >= 0) {
                    float* p = psum + (size_t)gcur * 128 + j * 8;
#pragma unroll
                    for (int t = 0; t < 8; ++t) atomicAdd(p + t, a[t]);
                }
                gcur = g;
#pragma unroll
                for (int t = 0; t < 8; ++t) a[t] = wv[t];
            } else {
#pragma unroll
                for (int t = 0; t < 8; ++t) a[t] += wv[t];
            }
        } else {
            u16x8 o;
#pragma unroll
            for (int t = 0; t < 8; ++t) o[t] = f2b(wv[t]);
            *(u16x8*)(hb + (size_t)row * 128 + j * 8) = o;
        }
    }
    if (FINAL && gcur >= 0) {
        float* p = psum + (size_t)gcur * 128 + j * 8;
#pragma unroll
        for (int t = 0; t < 8; ++t) atomicAdd(p + t, a[t]);
    }
}

__global__ void graph_mlp_kernel(const float* __restrict__ psum, const float* __restrict__ inv,
                                 const float* __restrict__ W1, const float* __restrict__ b1,
                                 const float* __restrict__ lng, const float* __restrict__ lnb,
                                 const float* __restrict__ W2, const float* __restrict__ b2,
                                 float* __restrict__ out) {
    __shared__ float t[128], t1[128], red[2];
    int g = blockIdx.x, d = threadIdx.x;
    int lane = d & 63, w = d >> 6;
    t[d] = psum[g * 128 + d] * inv[g];
    __syncthreads();
    float a = b1[d];
    for (int k = 0; k < 128; ++k) a += t[k] * W1[k * 128 + d];
    float s = a;
#pragma unroll
    for (int o = 1; o < 64; o <<= 1) s += __shfl_xor(s, o);
    if (lane == 0) red[w] = s;
    __syncthreads();
    float mu = (red[0] + red[1]) * (1.f / 128.f);
    float dv = a - mu;
    float qq = dv * dv;
#pragma unroll
    for (int o = 1; o < 64; o <<= 1) qq += __shfl_xor(qq, o);
    __syncthreads();
    if (lane == 0) red[w] = qq;
    __syncthreads();
    float var = (red[0] + red[1]) * (1.f / 128.f);
    float v = dv * rsqrtf(var + 1e-5f) * lng[d] + lnb[d];
    v = fmaxf(v, 0.f);
    t1[d] = v;
    __syncthreads();
    float o2 = b2[d];
    for (int k = 0; k < 128; ++k) o2 += t1[k] * W2[k * 128 + d];
    out[g * 128 + d] = o2;
}

extern "C" void kernel_launch(void* const* d_in, const int* in_sizes, int n_in,
                              void* d_out, int out_size, void* d_ws, size_t ws_size,
                              hipStream_t stream) {
    const float* x    = (const float*)d_in[0];
    const int*   edge = (const int*)d_in[1];
    const int*   src  = edge;
    const int*   dst  = edge + NEDGES;
    const int*   batch = (const int*)d_in[2];
    const float* nW   = (const float*)d_in[3];
    const float* nb   = (const float*)d_in[4];
    const float* W1s  = (const float*)d_in[5];
    const float* b1s  = (const float*)d_in[6];
    const float* W2s  = (const float*)d_in[7];
    const float* b2s  = (const float*)d_in[8];
    const float* bng  = (const float*)d_in[9];
    const float* bnb  = (const float*)d_in[10];
    const float* vne  = (const float*)d_in[11];
    const float* vW1  = (const float*)d_in[12];
    const float* vb1  = (const float*)d_in[13];
    const float* vW2  = (const float*)d_in[14];
    const float* vb2  = (const float*)d_in[15];
    const float* gW1  = (const float*)d_in[16];
    const float* gb1  = (const float*)d_in[17];
    const float* lng  = (const float*)d_in[18];
    const float* lnb  = (const float*)d_in[19];
    const float* gW2  = (const float*)d_in[20];
    const float* gb2  = (const float*)d_in[21];

    char* ws = (char*)d_ws;
    auto alloc = [&](size_t bytes) { char* p = ws; ws += (bytes + 255) & ~(size_t)255; return p; };
    float*  stats = (float*)alloc(256 * 4);                    // colsum+colsq
    float*  tmp   = (float*)alloc((size_t)NGRAPH * 128 * 4);   // per-layer pool partials
    float*  tmp2  = (float*)alloc((size_t)NGRAPH * 128 * 4);   // final pool partials
    ushort* hb    = (ushort*)alloc((size_t)NPAD * 128 * 2);    // h in bf16
    ushort* mbuf  = (ushort*)alloc((size_t)NPAD * 128 * 2);
    ushort* xb    = (ushort*)alloc((size_t)NPAD * 128 * 2);
    float*  vn    = (float*)alloc((size_t)NGRAPH * 128 * 4);
    ushort* w1t   = (ushort*)alloc((size_t)NLAYER * 256 * 128 * 2);
    ushort* w2t   = (ushort*)alloc((size_t)NLAYER * 128 * 256 * 2);
    float*  inv   = (float*)alloc((size_t)NGRAPH * 4);
    int*    deg   = (int*)alloc((size_t)NNODES * 4);
    int*    rs    = (int*)alloc((size_t)(NNODES + 1) * 4);
    int*    cursor= (int*)alloc((size_t)NNODES * 4);
    int*    csrc  = (int*)alloc((size_t)NEDGES * 4);
    int*    partials = (int*)alloc((size_t)SCAN_NB * 4);
    float*  colsum = stats;
    float*  colsq  = stats + 128;

    float* outN = (float*)d_out;
    float* outG = outN + (size_t)NNODES * 128;

    // stats + tmp + tmp2 are contiguous: one unconditional memset (vn_update keeps them
    // zeroed between layers/calls; this covers the first call after 0xAA poison).
    hipMemsetAsync(stats, 0, 1024 + 2 * (size_t)NGRAPH * 128 * 4, stream);
    hipMemsetAsync(deg, 0, (size_t)NNODES * 4, stream);

    // CSR build (edges constant across layers)
    deg_kernel<<<(NEDGES + 255) / 256, 256, 0, stream>>>(dst, deg);
    scan_part_kernel<<<SCAN_NB, 256, 0, stream>>>(deg, partials);
    scan_top_kernel<<<1, 512, 0, stream>>>(partials);
    scan_blocks_kernel<<<SCAN_NB, 256, 0, stream>>>(deg, partials, rs, cursor);
    csr_scatter_kernel<<<(NEDGES + 255) / 256, 256, 0, stream>>>(src, dst, cursor, csrc);
    gcnt_kernel<<<(NGRAPH + 255) / 256, 256, 0, stream>>>(batch, inv);

    prep_w_kernel<<<(2 * NLAYER * 128 * 256 + 255) / 256, 256, 0, stream>>>(W1s, W2s, w1t, w2t);
    node_embed_kernel<<<(NNODES * 128 + 255) / 256, 256, 0, stream>>>(x, nW, nb, hb);
    vn_init_kernel<<<(NGRAPH * 128 + 255) / 256, 256, 0, stream>>>(vne, vn);

    for (int i = 0; i < NLAYER; ++i) {
        gin_agg_kernel<<<(NNODES + 15) / 16, 256, 0, stream>>>(hb, rs, csrc, xb);
        fused_mlp_kernel<<<NPAD / 64, 256, 0, stream>>>(
            xb, w1t + (size_t)i * 256 * 128, b1s + i * 256,
            w2t + (size_t)i * 128 * 256, b2s + i * 128, mbuf, colsum, colsq);
        bn_pool_apply_kernel<<<(NNODES + 255) / 256, 512, 0, stream>>>(
            mbuf, colsum, colsq, bng + i * 128, bnb + i * 128, batch, hb, tmp, i > 0 ? 1 : 0);
        vn_update_kernel<<<NGRAPH, 128, 0, stream>>>(tmp, inv, vW1, vb1, vW2, vb2, vn, stats);
        if (i < NLAYER - 1)
            add_vn_kernel<0><<<(NNODES + 255) / 256, 512, 0, stream>>>(hb, vn, batch, nullptr, nullptr);
        else
            add_vn_kernel<1><<<(NNODES + 255) / 256, 512, 0, stream>>>(hb, vn, batch, outN, tmp2);
    }
    graph_mlp_kernel<<<NGRAPH, 128, 0, stream>>>(tmp2, inv, gW1, gb1, lng, lnb, gW2, gb2, outG);
}

// Round 8
// 875.806 us; speedup vs baseline: 1.3824x; 1.2780x over previous
//
#include <hip/hip_runtime.h>
#include <stdint.h>

#define NNODES 100000
#define NEDGES 600000
#define NGRAPH 2048
#define DD 128
#define NLAYER 5
#define NPAD 100096   // 782*128 = 1564*64
#define SCAN_NB 391   // ceil(NNODES/256)

typedef __attribute__((ext_vector_type(8))) __bf16 bf16x8;
typedef __attribute__((ext_vector_type(4))) float f32x4;
typedef __attribute__((ext_vector_type(8))) ushort u16x8;

__device__ __forceinline__ ushort f2b(float f) {
    union { float f; uint32_t u; } v; v.f = f;
    uint32_t r = v.u + 0x7FFFu + ((v.u >> 16) & 1u);
    return (ushort)(r >> 16);
}

__device__ __forceinline__ float b2f(ushort u) {
    union { uint32_t u; float f; } v; v.u = ((uint32_t)u) << 16; return v.f;
}

__device__ __forceinline__ void gload_lds16(const void* g, void* l) {
    __builtin_amdgcn_global_load_lds(
        (const __attribute__((address_space(1))) void*)g,
        (__attribute__((address_space(3))) void*)l, 16, 0, 0);
}

__global__ void prep_w_kernel(const float* __restrict__ W1s, const float* __restrict__ W2s,
                              ushort* __restrict__ w1t, ushort* __restrict__ w2t) {
    int idx = blockIdx.x * 256 + threadIdx.x;
    const int per = 128 * 256;
    if (idx < NLAYER * per) {
        int i = idx / per, rem = idx % per;
        int n = rem >> 7, k = rem & 127;          // w1t[i][n(256)][k(128)] = W1s[i][k][n]
        w1t[idx] = f2b(W1s[(size_t)i * per + k * 256 + n]);
    } else if (idx < 2 * NLAYER * per) {
        int j = idx - NLAYER * per;
        int i = j / per, rem = j % per;
        int n = rem >> 8, k = rem & 255;          // w2t[i][n(128)][k(256)] = W2s[i][k][n]
        w2t[j] = f2b(W2s[(size_t)i * per + k * 128 + n]);
    }
}

__global__ void node_embed_kernel(const float* __restrict__ x, const float* __restrict__ W,
                                  const float* __restrict__ b, ushort* __restrict__ hb) {
    int idx = blockIdx.x * 256 + threadIdx.x;
    if (idx >= NNODES * 128) return;
    int n = idx >> 7, d = idx & 127;
    float v = b[d];
#pragma unroll
    for (int k = 0; k < 9; ++k) v += x[n * 9 + k] * W[k * 128 + d];
    hb[(size_t)n * 128 + d] = f2b(v);
}

__global__ void vn_init_kernel(const float* __restrict__ vne, float* __restrict__ vn) {
    int idx = blockIdx.x * 256 + threadIdx.x;
    if (idx >= NGRAPH * 128) return;
    vn[idx] = vne[idx & 127];
}

// ---------- CSR build (once per call; edges constant across layers) ----------

__global__ void deg_kernel(const int* __restrict__ dst, int* __restrict__ deg) {
    int e = blockIdx.x * 256 + threadIdx.x;
    if (e < NEDGES) atomicAdd(&deg[dst[e]], 1);
}

__global__ void scan_part_kernel(const int* __restrict__ deg, int* __restrict__ partials) {
    int i = blockIdx.x * 256 + threadIdx.x;
    int lane = threadIdx.x & 63, w = threadIdx.x >> 6;
    int v = (i < NNODES) ? deg[i] : 0;
#pragma unroll
    for (int o = 1; o < 64; o <<= 1) v += __shfl_xor(v, o);
    __shared__ int ws[4];
    if (lane == 0) ws[w] = v;
    __syncthreads();
    if (threadIdx.x == 0) partials[blockIdx.x] = ws[0] + ws[1] + ws[2] + ws[3];
}

__global__ __launch_bounds__(512)
void scan_top_kernel(int* __restrict__ partials) {
    __shared__ int s[512];
    int t = threadIdx.x;
    int v = (t < SCAN_NB) ? partials[t] : 0;
    s[t] = v;
    __syncthreads();
#pragma unroll
    for (int o = 1; o < 512; o <<= 1) {
        int n = (t >= o) ? s[t - o] : 0;
        __syncthreads();
        s[t] += n;
        __syncthreads();
    }
    if (t < SCAN_NB) partials[t] = s[t] - v;   // exclusive
}

__global__ void scan_blocks_kernel(const int* __restrict__ deg, const int* __restrict__ partials,
                                   int* __restrict__ rs, int* __restrict__ cursor) {
    int i = blockIdx.x * 256 + threadIdx.x;
    int lane = threadIdx.x & 63, w = threadIdx.x >> 6;
    int v = (i < NNODES) ? deg[i] : 0;
    int x = v;
#pragma unroll
    for (int o = 1; o < 64; o <<= 1) {
        int n = __shfl_up(x, o);
        if (lane >= o) x += n;
    }
    __shared__ int ws[4];
    if (lane == 63) ws[w] = x;
    __syncthreads();
    if (threadIdx.x == 0) {
        int a = 0;
#pragma unroll
        for (int k = 0; k < 4; ++k) { int t = ws[k]; ws[k] = a; a += t; }
    }
    __syncthreads();
    int excl = (x - v) + ws[w] + partials[blockIdx.x];
    if (i < NNODES) { rs[i] = excl; cursor[i] = excl; }
    if (i == 0) rs[NNODES] = NEDGES;
}

__global__ void csr_scatter_kernel(const int* __restrict__ src, const int* __restrict__ dst,
                                   int* __restrict__ cursor, int* __restrict__ csrc) {
    int e = blockIdx.x * 256 + threadIdx.x;
    if (e < NEDGES) {
        int p = atomicAdd(&cursor[dst[e]], 1);
        csrc[p] = src[e];
    }
}

__device__ __forceinline__ int lbound(const int* __restrict__ b, int key) {
    int lo = 0, hi = NNODES;
    while (lo < hi) { int m = (lo + hi) >> 1; if (b[m] < key) lo = m + 1; else hi = m; }
    return lo;
}

// per-graph row range + 1/cnt
__global__ void gstart_kernel(const int* __restrict__ batch, int* __restrict__ gstart,
                              float* __restrict__ inv) {
    int g = blockIdx.x * 256 + threadIdx.x;
    if (g <= NGRAPH)
        gstart[g] = (g == NGRAPH) ? NNODES : lbound(batch, g);
    if (g < NGRAPH) {
        int c = lbound(batch, g + 1) - lbound(batch, g);
        inv[g] = 1.f / (float)(c > 0 ? c : 1);
    }
}

// ---------- GIN aggregation: xb[i] = bf16( h[i] + sum_{j->i} h[j] ), h in bf16 ----------

__global__ __launch_bounds__(256)
void gin_agg_kernel(const ushort* __restrict__ hb, const int* __restrict__ rs,
                    const int* __restrict__ csrc, ushort* __restrict__ xb) {
    int slot = threadIdx.x >> 4;
    int j = threadIdx.x & 15;
    int node = blockIdx.x * 16 + slot;
    if (node >= NNODES) return;
    int s = rs[node], e = rs[node + 1];
    u16x8 v0 = *(const u16x8*)(hb + (size_t)node * 128 + j * 8);
    float a[8];
#pragma unroll
    for (int t = 0; t < 8; ++t) a[t] = b2f(v0[t]);
    for (int k = s; k < e; ++k) {
        int sn = csrc[k];
        u16x8 v = *(const u16x8*)(hb + (size_t)sn * 128 + j * 8);
#pragma unroll
        for (int t = 0; t < 8; ++t) a[t] += b2f(v[t]);
    }
    u16x8 o;
#pragma unroll
    for (int t = 0; t < 8; ++t) o[t] = f2b(a[t]);
    *(u16x8*)(xb + (size_t)node * 128 + j * 8) = o;
}

// ---------- fused MLP v3: 64-row tile, 4 waves, async A staging ----------
__global__ __launch_bounds__(256)
void fused_mlp_kernel(const ushort* __restrict__ A, const ushort* __restrict__ W1,
                      const float* __restrict__ b1, const ushort* __restrict__ W2,
                      const float* __restrict__ b2, ushort* __restrict__ out_b,
                      float* __restrict__ stat_sum, float* __restrict__ stat_sq) {
    __shared__ __align__(16) ushort lA[8192];     // 16KB: [ks:4][q:4][row:64][8]
    __shared__ __align__(16) ushort mid[16384];   // 32KB: [g2:32][row:64][8]
    const int tid = threadIdx.x;
    const int lane = tid & 63, w = tid >> 6;
    const int q = lane >> 4, l16 = lane & 15;
    const int rb = blockIdx.x * 64;

#pragma unroll
    for (int p = 0; p < 4; ++p) {
        const ushort* gsrc = A + (size_t)(rb + lane) * 128 + p * 32 + w * 8;
        gload_lds16(gsrc, &lA[(size_t)(p * 256 + w * 64 + lane) * 8]);
    }
    __syncthreads();

    f32x4 acc1[4][4] = {};
#pragma unroll
    for (int ks = 0; ks < 4; ++ks) {
        bf16x8 af[4], bw[4];
#pragma unroll
        for (int mi = 0; mi < 4; ++mi)
            af[mi] = *(const bf16x8*)&lA[ks * 2048 + q * 512 + (mi * 16 + l16) * 8];
#pragma unroll
        for (int ni = 0; ni < 4; ++ni)
            bw[ni] = *(const bf16x8*)(W1 + (size_t)(w * 64 + ni * 16 + l16) * 128 + ks * 32 + q * 8);
#pragma unroll
        for (int mi = 0; mi < 4; ++mi)
#pragma unroll
            for (int ni = 0; ni < 4; ++ni)
                acc1[mi][ni] = __builtin_amdgcn_mfma_f32_16x16x32_bf16(af[mi], bw[ni], acc1[mi][ni], 0, 0, 0);
    }

#pragma unroll
    for (int ni = 0; ni < 4; ++ni) {
        int col = w * 64 + ni * 16 + l16;
        float bs = b1[col];
        int g2 = col >> 3, jj = col & 7;
#pragma unroll
        for (int mi = 0; mi < 4; ++mi) {
            int rowb = mi * 16 + q * 4;
#pragma unroll
            for (int r = 0; r < 4; ++r) {
                float v = acc1[mi][ni][r] + bs;
                v = v > 0.f ? v : 0.f;
                mid[g2 * 512 + (rowb + r) * 8 + jj] = f2b(v);
            }
        }
    }
    __syncthreads();

    f32x4 acc2[4][2] = {};
#pragma unroll
    for (int ks = 0; ks < 8; ++ks) {
        bf16x8 af[4], bw[2];
#pragma unroll
        for (int mi = 0; mi < 4; ++mi)
            af[mi] = *(const bf16x8*)&mid[(ks * 4 + q) * 512 + (mi * 16 + l16) * 8];
#pragma unroll
        for (int ni = 0; ni < 2; ++ni)
            bw[ni] = *(const bf16x8*)(W2 + (size_t)(w * 32 + ni * 16 + l16) * 256 + ks * 32 + q * 8);
#pragma unroll
        for (int mi = 0; mi < 4; ++mi)
#pragma unroll
            for (int ni = 0; ni < 2; ++ni)
                acc2[mi][ni] = __builtin_amdgcn_mfma_f32_16x16x32_bf16(af[mi], bw[ni], acc2[mi][ni], 0, 0, 0);
    }

#pragma unroll
    for (int ni = 0; ni < 2; ++ni) {
        int col = w * 32 + ni * 16 + l16;
        float bs = b2[col];
        float s = 0.f, sq = 0.f;
#pragma unroll
        for (int mi = 0; mi < 4; ++mi) {
            int row = rb + mi * 16 + q * 4;
#pragma unroll
            for (int r = 0; r < 4; ++r) {
                float v = acc2[mi][ni][r] + bs;
                out_b[(size_t)(row + r) * 128 + col] = f2b(v);
                if (row + r < NNODES) { s += v; sq += v * v; }
            }
        }
        s  += __shfl_xor(s, 16);  s  += __shfl_xor(s, 32);
        sq += __shfl_xor(sq, 16); sq += __shfl_xor(sq, 32);
        if (lane < 16) {
            atomicAdd(&stat_sum[col], s);
            atomicAdd(&stat_sq[col], sq);
        }
    }
}

// ---------- BN finalize (per-block recompute) + apply + residual; flat, no atomics ----------
__global__ __launch_bounds__(512)
void bn_apply_kernel(const ushort* __restrict__ m, const float* __restrict__ colsum,
                     const float* __restrict__ colsq, const float* __restrict__ bng,
                     const float* __restrict__ bnb, ushort* __restrict__ hb, int resid) {
    __shared__ float sC[128], sS[128];
    if (threadIdx.x < 128) {
        int d = threadIdx.x;
        float mu = colsum[d] * (1.f / NNODES);
        float var = colsq[d] * (1.f / NNODES) - mu * mu;
        var = var < 0.f ? 0.f : var;
        float sc = bng[d] * rsqrtf(var + 1e-5f);
        sC[d] = sc;
        sS[d] = bnb[d] - mu * sc;
    }
    __syncthreads();
    int t = blockIdx.x * 512 + threadIdx.x;   // (row, j16) units
    if (t >= NNODES * 16) return;
    int row = t >> 4, j = t & 15;
    u16x8 mu8 = *(const u16x8*)(m + (size_t)row * 128 + j * 8);
    float wv[8];
#pragma unroll
    for (int k = 0; k < 8; ++k)
        wv[k] = fmaxf(b2f(mu8[k]) * sC[j * 8 + k] + sS[j * 8 + k], 0.f);
    if (resid) {
        u16x8 hp = *(const u16x8*)(hb + (size_t)row * 128 + j * 8);
#pragma unroll
        for (int k = 0; k < 8; ++k) wv[k] += b2f(hp[k]);
    }
    u16x8 o;
#pragma unroll
    for (int k = 0; k < 8; ++k) o[k] = f2b(wv[k]);
    *(u16x8*)(hb + (size_t)row * 128 + j * 8) = o;
}

// ---------- vn update with in-kernel per-graph pooling (no atomics, no psum) ----------
__global__ void vn_update_kernel(const ushort* __restrict__ hb, const int* __restrict__ gstart,
                                 const float* __restrict__ inv,
                                 const float* __restrict__ W1, const float* __restrict__ b1,
                                 const float* __restrict__ W2, const float* __restrict__ b2,
                                 float* __restrict__ vn, float* __restrict__ stats) {
    __shared__ float t[128], t1[128];
    int g = blockIdx.x, d = threadIdx.x;
    int s = gstart[g], e = gstart[g + 1];
    float acc = 0.f;
    for (int r = s; r < e; ++r) acc += b2f(hb[(size_t)r * 128 + d]);
    t[d] = acc * inv[g];
    if (g == 0) { stats[d] = 0.f; stats[128 + d] = 0.f; }   // zero stats for next layer
    __syncthreads();
    float a = b1[d];
    for (int k = 0; k < 128; ++k) a += t[k] * W1[k * 128 + d];
    t1[d] = fmaxf(a, 0.f);
    __syncthreads();
    float o = b2[d];
    for (int k = 0; k < 128; ++k) o += t1[k] * W2[k * 128 + d];
    vn[g * 128 + d] += o;
}

// ---------- h += vn[batch]; flat. FINAL: write f32 outN instead ----------
template<int FINAL>
__global__ __launch_bounds__(512)
void add_vn_kernel(ushort* __restrict__ hb, const float* __restrict__ vn,
                   const int* __restrict__ batch, float* __restrict__ outN) {
    int t = blockIdx.x * 512 + threadIdx.x;
    if (t >= NNODES * 16) return;
    int row = t >> 4, j = t & 15;
    int g = batch[row];
    float4 v0 = ((const float4*)(vn + (size_t)g * 128))[j * 2];
    float4 v1 = ((const float4*)(vn + (size_t)g * 128))[j * 2 + 1];
    u16x8 hv = *(const u16x8*)(hb + (size_t)row * 128 + j * 8);
    float wv[8];
    wv[0] = b2f(hv[0]) + v0.x; wv[1] = b2f(hv[1]) + v0.y;
    wv[2] = b2f(hv[2]) + v0.z; wv[3] = b2f(hv[3]) + v0.w;
    wv[4] = b2f(hv[4]) + v1.x; wv[5] = b2f(hv[5]) + v1.y;
    wv[6] = b2f(hv[6]) + v1.z; wv[7] = b2f(hv[7]) + v1.w;
    if (FINAL) {
        float4* op = (float4*)(outN + (size_t)row * 128 + j * 8);
        op[0] = make_float4(wv[0], wv[1], wv[2], wv[3]);
        op[1] = make_float4(wv[4], wv[5], wv[6], wv[7]);
    } else {
        u16x8 o;
#pragma unroll
        for (int k = 0; k < 8; ++k) o[k] = f2b(wv[k]);
        *(u16x8*)(hb + (size_t)row * 128 + j * 8) = o;
    }
}

// ---------- graph MLP with in-kernel final pooling (pool(hb)+vn == pool(outN)) ----------
__global__ void graph_mlp_kernel(const ushort* __restrict__ hb, const int* __restrict__ gstart,
                                 const float* __restrict__ inv, const float* __restrict__ vn,
                                 const float* __restrict__ W1, const float* __restrict__ b1,
                                 const float* __restrict__ lng, const float* __restrict__ lnb,
                                 const float* __restrict__ W2, const float* __restrict__ b2,
                                 float* __restrict__ out) {
    __shared__ float t[128], t1[128], red[2];
    int g = blockIdx.x, d = threadIdx.x;
    int lane = d & 63, w = d >> 6;
    int s = gstart[g], e = gstart[g + 1];
    float acc = 0.f;
    for (int r = s; r < e; ++r) acc += b2f(hb[(size_t)r * 128 + d]);
    t[d] = (e > s) ? (acc * inv[g] + vn[(size_t)g * 128 + d]) : 0.f;
    __syncthreads();
    float a = b1[d];
    for (int k = 0; k < 128; ++k) a += t[k] * W1[k * 128 + d];
    float ssum = a;
#pragma unroll
    for (int o = 1; o < 64; o <<= 1) ssum += __shfl_xor(ssum, o);
    if (lane == 0) red[w] = ssum;
    __syncthreads();
    float mu = (red[0] + red[1]) * (1.f / 128.f);
    float dv = a - mu;
    float qq = dv * dv;
#pragma unroll
    for (int o = 1; o < 64; o <<= 1) qq += __shfl_xor(qq, o);
    __syncthreads();
    if (lane == 0) red[w] = qq;
    __syncthreads();
    float var = (red[0] + red[1]) * (1.f / 128.f);
    float v = dv * rsqrtf(var + 1e-5f) * lng[d] + lnb[d];
    v = fmaxf(v, 0.f);
    t1[d] = v;
    __syncthreads();
    float o2 = b2[d];
    for (int k = 0; k < 128; ++k) o2 += t1[k] * W2[k * 128 + d];
    out[g * 128 + d] = o2;
}

extern "C" void kernel_launch(void* const* d_in, const int* in_sizes, int n_in,
                              void* d_out, int out_size, void* d_ws, size_t ws_size,
                              hipStream_t stream) {
    const float* x    = (const float*)d_in[0];
    const int*   edge = (const int*)d_in[1];
    const int*   src  = edge;
    const int*   dst  = edge + NEDGES;
    const int*   batch = (const int*)d_in[2];
    const float* nW   = (const float*)d_in[3];
    const float* nb   = (const float*)d_in[4];
    const float* W1s  = (const float*)d_in[5];
    const float* b1s  = (const float*)d_in[6];
    const float* W2s  = (const float*)d_in[7];
    const float* b2s  = (const float*)d_in[8];
    const float* bng  = (const float*)d_in[9];
    const float* bnb  = (const float*)d_in[10];
    const float* vne  = (const float*)d_in[11];
    const float* vW1  = (const float*)d_in[12];
    const float* vb1  = (const float*)d_in[13];
    const float* vW2  = (const float*)d_in[14];
    const float* vb2  = (const float*)d_in[15];
    const float* gW1  = (const float*)d_in[16];
    const float* gb1  = (const float*)d_in[17];
    const float* lng  = (const float*)d_in[18];
    const float* lnb  = (const float*)d_in[19];
    const float* gW2  = (const float*)d_in[20];
    const float* gb2  = (const float*)d_in[21];

    char* ws = (char*)d_ws;
    auto alloc = [&](size_t bytes) { char* p = ws; ws += (bytes + 255) & ~(size_t)255; return p; };
    float*  stats = (float*)alloc(256 * 4);                    // colsum+colsq
    ushort* hb    = (ushort*)alloc((size_t)NPAD * 128 * 2);    // h in bf16
    ushort* mbuf  = (ushort*)alloc((size_t)NPAD * 128 * 2);
    ushort* xb    = (ushort*)alloc((size_t)NPAD * 128 * 2);
    float*  vn    = (float*)alloc((size_t)NGRAPH * 128 * 4);
    ushort* w1t   = (ushort*)alloc((size_t)NLAYER * 256 * 128 * 2);
    ushort* w2t   = (ushort*)alloc((size_t)NLAYER * 128 * 256 * 2);
    float*  inv   = (float*)alloc((size_t)NGRAPH * 4);
    int*    gstart= (int*)alloc((size_t)(NGRAPH + 1) * 4);
    int*    deg   = (int*)alloc((size_t)NNODES * 4);
    int*    rs    = (int*)alloc((size_t)(NNODES + 1) * 4);
    int*    cursor= (int*)alloc((size_t)NNODES * 4);
    int*    csrc  = (int*)alloc((size_t)NEDGES * 4);
    int*    partials = (int*)alloc((size_t)SCAN_NB * 4);
    float*  colsum = stats;
    float*  colsq  = stats + 128;

    float* outN = (float*)d_out;
    float* outG = outN + (size_t)NNODES * 128;

    hipMemsetAsync(stats, 0, 1024, stream);
    hipMemsetAsync(deg, 0, (size_t)NNODES * 4, stream);

    // CSR build (edges constant across layers)
    deg_kernel<<<(NEDGES + 255) / 256, 256, 0, stream>>>(dst, deg);
    scan_part_kernel<<<SCAN_NB, 256, 0, stream>>>(deg, partials);
    scan_top_kernel<<<1, 512, 0, stream>>>(partials);
    scan_blocks_kernel<<<SCAN_NB, 256, 0, stream>>>(deg, partials, rs, cursor);
    csr_scatter_kernel<<<(NEDGES + 255) / 256, 256, 0, stream>>>(src, dst, cursor, csrc);
    gstart_kernel<<<(NGRAPH + 256) / 256, 256, 0, stream>>>(batch, gstart, inv);

    prep_w_kernel<<<(2 * NLAYER * 128 * 256 + 255) / 256, 256, 0, stream>>>(W1s, W2s, w1t, w2t);
    node_embed_kernel<<<(NNODES * 128 + 255) / 256, 256, 0, stream>>>(x, nW, nb, hb);
    vn_init_kernel<<<(NGRAPH * 128 + 255) / 256, 256, 0, stream>>>(vne, vn);

    const int flatNB = (NNODES * 16 + 511) / 512;   // 3125
    for (int i = 0; i < NLAYER; ++i) {
        gin_agg_kernel<<<(NNODES + 15) / 16, 256, 0, stream>>>(hb, rs, csrc, xb);
        fused_mlp_kernel<<<NPAD / 64, 256, 0, stream>>>(
            xb, w1t + (size_t)i * 256 * 128, b1s + i * 256,
            w2t + (size_t)i * 128 * 256, b2s + i * 128, mbuf, colsum, colsq);
        bn_apply_kernel<<<flatNB, 512, 0, stream>>>(
            mbuf, colsum, colsq, bng + i * 128, bnb + i * 128, hb, i > 0 ? 1 : 0);
        vn_update_kernel<<<NGRAPH, 128, 0, stream>>>(hb, gstart, inv, vW1, vb1, vW2, vb2, vn, stats);
        if (i < NLAYER - 1)
            add_vn_kernel<0><<<flatNB, 512, 0, stream>>>(hb, vn, batch, nullptr);
        else
            add_vn_kernel<1><<<flatNB, 512, 0, stream>>>(hb, vn, batch, outN);
    }
    graph_mlp_kernel<<<NGRAPH, 128, 0, stream>>>(hb, gstart, inv, vn, gW1, gb1, lng, lnb, gW2, gb2, outG);
}

// Round 9
// 855.258 us; speedup vs baseline: 1.4156x; 1.0240x over previous
//
#include <hip/hip_runtime.h>
#include <stdint.h>

#define NNODES 100000
#define NEDGES 600000
#define NGRAPH 2048
#define DD 128
#define NLAYER 5
#define NPAD 100096   // 782*128 = 1564*64
#define SCAN_NB 391   // ceil(NNODES/256)

typedef __attribute__((ext_vector_type(8))) __bf16 bf16x8;
typedef __attribute__((ext_vector_type(4))) float f32x4;
typedef __attribute__((ext_vector_type(8))) ushort u16x8;

__device__ __forceinline__ ushort f2b(float f) {
    union { float f; uint32_t u; } v; v.f = f;
    uint32_t r = v.u + 0x7FFFu + ((v.u >> 16) & 1u);
    return (ushort)(r >> 16);
}

__device__ __forceinline__ float b2f(ushort u) {
    union { uint32_t u; float f; } v; v.u = ((uint32_t)u) << 16; return v.f;
}

__device__ __forceinline__ void gload_lds16(const void* g, void* l) {
    __builtin_amdgcn_global_load_lds(
        (const __attribute__((address_space(1))) void*)g,
        (__attribute__((address_space(3))) void*)l, 16, 0, 0);
}

__global__ void prep_w_kernel(const float* __restrict__ W1s, const float* __restrict__ W2s,
                              ushort* __restrict__ w1t, ushort* __restrict__ w2t) {
    int idx = blockIdx.x * 256 + threadIdx.x;
    const int per = 128 * 256;
    if (idx < NLAYER * per) {
        int i = idx / per, rem = idx % per;
        int n = rem >> 7, k = rem & 127;          // w1t[i][n(256)][k(128)] = W1s[i][k][n]
        w1t[idx] = f2b(W1s[(size_t)i * per + k * 256 + n]);
    } else if (idx < 2 * NLAYER * per) {
        int j = idx - NLAYER * per;
        int i = j / per, rem = j % per;
        int n = rem >> 8, k = rem & 255;          // w2t[i][n(128)][k(256)] = W2s[i][k][n]
        w2t[j] = f2b(W2s[(size_t)i * per + k * 128 + n]);
    }
}

__global__ void node_embed_kernel(const float* __restrict__ x, const float* __restrict__ W,
                                  const float* __restrict__ b, ushort* __restrict__ hb) {
    int idx = blockIdx.x * 256 + threadIdx.x;
    if (idx >= NNODES * 128) return;
    int n = idx >> 7, d = idx & 127;
    float v = b[d];
#pragma unroll
    for (int k = 0; k < 9; ++k) v += x[n * 9 + k] * W[k * 128 + d];
    hb[(size_t)n * 128 + d] = f2b(v);
}

__global__ void vn_init_kernel(const float* __restrict__ vne, float* __restrict__ vn) {
    int idx = blockIdx.x * 256 + threadIdx.x;
    if (idx >= NGRAPH * 128) return;
    vn[idx] = vne[idx & 127];
}

// ---------- CSR build (once per call; edges constant across layers) ----------

__global__ void deg_kernel(const int* __restrict__ dst, int* __restrict__ deg) {
    int e = blockIdx.x * 256 + threadIdx.x;
    if (e < NEDGES) atomicAdd(&deg[dst[e]], 1);
}

__global__ void scan_part_kernel(const int* __restrict__ deg, int* __restrict__ partials) {
    int i = blockIdx.x * 256 + threadIdx.x;
    int lane = threadIdx.x & 63, w = threadIdx.x >> 6;
    int v = (i < NNODES) ? deg[i] : 0;
#pragma unroll
    for (int o = 1; o < 64; o <<= 1) v += __shfl_xor(v, o);
    __shared__ int ws[4];
    if (lane == 0) ws[w] = v;
    __syncthreads();
    if (threadIdx.x == 0) partials[blockIdx.x] = ws[0] + ws[1] + ws[2] + ws[3];
}

__global__ __launch_bounds__(512)
void scan_top_kernel(int* __restrict__ partials) {
    __shared__ int s[512];
    int t = threadIdx.x;
    int v = (t < SCAN_NB) ? partials[t] : 0;
    s[t] = v;
    __syncthreads();
#pragma unroll
    for (int o = 1; o < 512; o <<= 1) {
        int n = (t >= o) ? s[t - o] : 0;
        __syncthreads();
        s[t] += n;
        __syncthreads();
    }
    if (t < SCAN_NB) partials[t] = s[t] - v;   // exclusive
}

__global__ void scan_blocks_kernel(const int* __restrict__ deg, const int* __restrict__ partials,
                                   int* __restrict__ rs, int* __restrict__ cursor) {
    int i = blockIdx.x * 256 + threadIdx.x;
    int lane = threadIdx.x & 63, w = threadIdx.x >> 6;
    int v = (i < NNODES) ? deg[i] : 0;
    int x = v;
#pragma unroll
    for (int o = 1; o < 64; o <<= 1) {
        int n = __shfl_up(x, o);
        if (lane >= o) x += n;
    }
    __shared__ int ws[4];
    if (lane == 63) ws[w] = x;
    __syncthreads();
    if (threadIdx.x == 0) {
        int a = 0;
#pragma unroll
        for (int k = 0; k < 4; ++k) { int t = ws[k]; ws[k] = a; a += t; }
    }
    __syncthreads();
    int excl = (x - v) + ws[w] + partials[blockIdx.x];
    if (i < NNODES) { rs[i] = excl; cursor[i] = excl; }
    if (i == 0) rs[NNODES] = NEDGES;
}

__global__ void csr_scatter_kernel(const int* __restrict__ src, const int* __restrict__ dst,
                                   int* __restrict__ cursor, int* __restrict__ csrc) {
    int e = blockIdx.x * 256 + threadIdx.x;
    if (e < NEDGES) {
        int p = atomicAdd(&cursor[dst[e]], 1);
        csrc[p] = src[e];
    }
}

__device__ __forceinline__ int lbound(const int* __restrict__ b, int key) {
    int lo = 0, hi = NNODES;
    while (lo < hi) { int m = (lo + hi) >> 1; if (b[m] < key) lo = m + 1; else hi = m; }
    return lo;
}

// per-graph row range + 1/cnt
__global__ void gstart_kernel(const int* __restrict__ batch, int* __restrict__ gstart,
                              float* __restrict__ inv) {
    int g = blockIdx.x * 256 + threadIdx.x;
    if (g <= NGRAPH)
        gstart[g] = (g == NGRAPH) ? NNODES : lbound(batch, g);
    if (g < NGRAPH) {
        int c = lbound(batch, g + 1) - lbound(batch, g);
        inv[g] = 1.f / (float)(c > 0 ? c : 1);
    }
}

// ---------- GIN aggregation: xb[i] = bf16( h[i] + sum_{j->i} h[j] ), h in bf16 ----------

__global__ __launch_bounds__(256)
void gin_agg_kernel(const ushort* __restrict__ hb, const int* __restrict__ rs,
                    const int* __restrict__ csrc, ushort* __restrict__ xb) {
    int slot = threadIdx.x >> 4;
    int j = threadIdx.x & 15;
    int node = blockIdx.x * 16 + slot;
    if (node >= NNODES) return;
    int s = rs[node], e = rs[node + 1];
    u16x8 v0 = *(const u16x8*)(hb + (size_t)node * 128 + j * 8);
    float a[8];
#pragma unroll
    for (int t = 0; t < 8; ++t) a[t] = b2f(v0[t]);
    for (int k = s; k < e; ++k) {
        int sn = csrc[k];
        u16x8 v = *(const u16x8*)(hb + (size_t)sn * 128 + j * 8);
#pragma unroll
        for (int t = 0; t < 8; ++t) a[t] += b2f(v[t]);
    }
    u16x8 o;
#pragma unroll
    for (int t = 0; t < 8; ++t) o[t] = f2b(a[t]);
    *(u16x8*)(xb + (size_t)node * 128 + j * 8) = o;
}

// ---------- fused MLP v4: weights in registers, 2 tiles/block, async A pipeline ----------
// A: [NPAD][128] bf16. W1: [256][128]. W2: [128][256]. out_b: [NPAD][128] bf16.
#define MLP_GRID 782   // NPAD/64/2
__global__ __launch_bounds__(256, 2)
void fused_mlp_kernel(const ushort* __restrict__ A, const ushort* __restrict__ W1,
                      const float* __restrict__ b1, const ushort* __restrict__ W2,
                      const float* __restrict__ b2, ushort* __restrict__ out_b,
                      float* __restrict__ stat_sum, float* __restrict__ stat_sq) {
    __shared__ __align__(16) ushort lA[8192];     // 16KB: [ks:4][q:4][row:64][8]
    __shared__ __align__(16) ushort mid[16384];   // 32KB: [g2:32][row:64][8]
    const int tid = threadIdx.x;
    const int lane = tid & 63, w = tid >> 6;
    const int q = lane >> 4, l16 = lane & 15;

    // ---- preload all weight fragments for this wave's n-quadrants into registers ----
    bf16x8 w1f[4][4], w2f[8][2];
#pragma unroll
    for (int ks = 0; ks < 4; ++ks)
#pragma unroll
        for (int ni = 0; ni < 4; ++ni)
            w1f[ks][ni] = *(const bf16x8*)(W1 + (size_t)(w * 64 + ni * 16 + l16) * 128 + ks * 32 + q * 8);
#pragma unroll
    for (int ks = 0; ks < 8; ++ks)
#pragma unroll
        for (int ni = 0; ni < 2; ++ni)
            w2f[ks][ni] = *(const bf16x8*)(W2 + (size_t)(w * 32 + ni * 16 + l16) * 256 + ks * 32 + q * 8);

    // stage tile 0
    {
        int rb = blockIdx.x * 128;
#pragma unroll
        for (int p = 0; p < 4; ++p)
            gload_lds16(A + (size_t)(rb + lane) * 128 + p * 32 + w * 8,
                        &lA[(size_t)(p * 256 + w * 64 + lane) * 8]);
    }

    for (int tt = 0; tt < 2; ++tt) {
        const int rb = blockIdx.x * 128 + tt * 64;
        __syncthreads();   // drains vmcnt (stage done) + orders mid reuse

        // ---- phase 1: C1[64][256] = A@W1 from LDS x regs ----
        f32x4 acc1[4][4] = {};
#pragma unroll
        for (int ks = 0; ks < 4; ++ks) {
            bf16x8 af[4];
#pragma unroll
            for (int mi = 0; mi < 4; ++mi)
                af[mi] = *(const bf16x8*)&lA[ks * 2048 + q * 512 + (mi * 16 + l16) * 8];
#pragma unroll
            for (int mi = 0; mi < 4; ++mi)
#pragma unroll
                for (int ni = 0; ni < 4; ++ni)
                    acc1[mi][ni] = __builtin_amdgcn_mfma_f32_16x16x32_bf16(af[mi], w1f[ks][ni], acc1[mi][ni], 0, 0, 0);
        }

        // relu(C1+b1) -> bf16 -> mid [g2][row][8]
#pragma unroll
        for (int ni = 0; ni < 4; ++ni) {
            int col = w * 64 + ni * 16 + l16;
            float bs = b1[col];
            int g2 = col >> 3, jj = col & 7;
#pragma unroll
            for (int mi = 0; mi < 4; ++mi) {
                int rowb = mi * 16 + q * 4;
#pragma unroll
                for (int r = 0; r < 4; ++r) {
                    float v = acc1[mi][ni][r] + bs;
                    v = v > 0.f ? v : 0.f;
                    mid[g2 * 512 + (rowb + r) * 8 + jj] = f2b(v);
                }
            }
        }
        __syncthreads();   // mid visible; lA reads done -> safe to restage

        // stage next tile (overlaps phase 2)
        if (tt == 0) {
            int rb2 = blockIdx.x * 128 + 64;
#pragma unroll
            for (int p = 0; p < 4; ++p)
                gload_lds16(A + (size_t)(rb2 + lane) * 128 + p * 32 + w * 8,
                            &lA[(size_t)(p * 256 + w * 64 + lane) * 8]);
        }

        // ---- phase 2: C2[64][128] = mid@W2 + b2 ----
        f32x4 acc2[4][2] = {};
#pragma unroll
        for (int ks = 0; ks < 8; ++ks) {
            bf16x8 af[4];
#pragma unroll
            for (int mi = 0; mi < 4; ++mi)
                af[mi] = *(const bf16x8*)&mid[(ks * 4 + q) * 512 + (mi * 16 + l16) * 8];
#pragma unroll
            for (int mi = 0; mi < 4; ++mi)
#pragma unroll
                for (int ni = 0; ni < 2; ++ni)
                    acc2[mi][ni] = __builtin_amdgcn_mfma_f32_16x16x32_bf16(af[mi], w2f[ks][ni], acc2[mi][ni], 0, 0, 0);
        }

#pragma unroll
        for (int ni = 0; ni < 2; ++ni) {
            int col = w * 32 + ni * 16 + l16;
            float bs = b2[col];
            float s = 0.f, sq = 0.f;
#pragma unroll
            for (int mi = 0; mi < 4; ++mi) {
                int row = rb + mi * 16 + q * 4;
#pragma unroll
                for (int r = 0; r < 4; ++r) {
                    float v = acc2[mi][ni][r] + bs;
                    out_b[(size_t)(row + r) * 128 + col] = f2b(v);
                    if (row + r < NNODES) { s += v; sq += v * v; }
                }
            }
            s  += __shfl_xor(s, 16);  s  += __shfl_xor(s, 32);
            sq += __shfl_xor(sq, 16); sq += __shfl_xor(sq, 32);
            if (lane < 16) {
                atomicAdd(&stat_sum[col], s);
                atomicAdd(&stat_sq[col], sq);
            }
        }
    }
}

// ---------- BN finalize (per-block recompute) + apply + residual; flat, no atomics ----------
__global__ __launch_bounds__(512)
void bn_apply_kernel(const ushort* __restrict__ m, const float* __restrict__ colsum,
                     const float* __restrict__ colsq, const float* __restrict__ bng,
                     const float* __restrict__ bnb, ushort* __restrict__ hb, int resid) {
    __shared__ float sC[128], sS[128];
    if (threadIdx.x < 128) {
        int d = threadIdx.x;
        float mu = colsum[d] * (1.f / NNODES);
        float var = colsq[d] * (1.f / NNODES) - mu * mu;
        var = var < 0.f ? 0.f : var;
        float sc = bng[d] * rsqrtf(var + 1e-5f);
        sC[d] = sc;
        sS[d] = bnb[d] - mu * sc;
    }
    __syncthreads();
    int t = blockIdx.x * 512 + threadIdx.x;   // (row, j16) units
    if (t >= NNODES * 16) return;
    int row = t >> 4, j = t & 15;
    u16x8 mu8 = *(const u16x8*)(m + (size_t)row * 128 + j * 8);
    float wv[8];
#pragma unroll
    for (int k = 0; k < 8; ++k)
        wv[k] = fmaxf(b2f(mu8[k]) * sC[j * 8 + k] + sS[j * 8 + k], 0.f);
    if (resid) {
        u16x8 hp = *(const u16x8*)(hb + (size_t)row * 128 + j * 8);
#pragma unroll
        for (int k = 0; k < 8; ++k) wv[k] += b2f(hp[k]);
    }
    u16x8 o;
#pragma unroll
    for (int k = 0; k < 8; ++k) o[k] = f2b(wv[k]);
    *(u16x8*)(hb + (size_t)row * 128 + j * 8) = o;
}

// ---------- vn update with in-kernel per-graph pooling (no atomics, no psum) ----------
__global__ void vn_update_kernel(const ushort* __restrict__ hb, const int* __restrict__ gstart,
                                 const float* __restrict__ inv,
                                 const float* __restrict__ W1, const float* __restrict__ b1,
                                 const float* __restrict__ W2, const float* __restrict__ b2,
                                 float* __restrict__ vn, float* __restrict__ stats) {
    __shared__ float t[128], t1[128];
    int g = blockIdx.x, d = threadIdx.x;
    int s = gstart[g], e = gstart[g + 1];
    float acc = 0.f;
    for (int r = s; r < e; ++r) acc += b2f(hb[(size_t)r * 128 + d]);
    t[d] = acc * inv[g];
    if (g == 0) { stats[d] = 0.f; stats[128 + d] = 0.f; }   // zero stats for next layer
    __syncthreads();
    float a = b1[d];
    for (int k = 0; k < 128; ++k) a += t[k] * W1[k * 128 + d];
    t1[d] = fmaxf(a, 0.f);
    __syncthreads();
    float o = b2[d];
    for (int k = 0; k < 128; ++k) o += t1[k] * W2[k * 128 + d];
    vn[g * 128 + d] += o;
}

// ---------- h += vn[batch]; flat. FINAL: write f32 outN instead ----------
template<int FINAL>
__global__ __launch_bounds__(512)
void add_vn_kernel(ushort* __restrict__ hb, const float* __restrict__ vn,
                   const int* __restrict__ batch, float* __restrict__ outN) {
    int t = blockIdx.x * 512 + threadIdx.x;
    if (t >= NNODES * 16) return;
    int row = t >> 4, j = t & 15;
    int g = batch[row];
    float4 v0 = ((const float4*)(vn + (size_t)g * 128))[j * 2];
    float4 v1 = ((const float4*)(vn + (size_t)g * 128))[j * 2 + 1];
    u16x8 hv = *(const u16x8*)(hb + (size_t)row * 128 + j * 8);
    float wv[8];
    wv[0] = b2f(hv[0]) + v0.x; wv[1] = b2f(hv[1]) + v0.y;
    wv[2] = b2f(hv[2]) + v0.z; wv[3] = b2f(hv[3]) + v0.w;
    wv[4] = b2f(hv[4]) + v1.x; wv[5] = b2f(hv[5]) + v1.y;
    wv[6] = b2f(hv[6]) + v1.z; wv[7] = b2f(hv[7]) + v1.w;
    if (FINAL) {
        float4* op = (float4*)(outN + (size_t)row * 128 + j * 8);
        op[0] = make_float4(wv[0], wv[1], wv[2], wv[3]);
        op[1] = make_float4(wv[4], wv[5], wv[6], wv[7]);
    } else {
        u16x8 o;
#pragma unroll
        for (int k = 0; k < 8; ++k) o[k] = f2b(wv[k]);
        *(u16x8*)(hb + (size_t)row * 128 + j * 8) = o;
    }
}

// ---------- graph MLP with in-kernel final pooling (pool(hb)+vn == pool(outN)) ----------
__global__ void graph_mlp_kernel(const ushort* __restrict__ hb, const int* __restrict__ gstart,
                                 const float* __restrict__ inv, const float* __restrict__ vn,
                                 const float* __restrict__ W1, const float* __restrict__ b1,
                                 const float* __restrict__ lng, const float* __restrict__ lnb,
                                 const float* __restrict__ W2, const float* __restrict__ b2,
                                 float* __restrict__ out) {
    __shared__ float t[128], t1[128], red[2];
    int g = blockIdx.x, d = threadIdx.x;
    int lane = d & 63, w = d >> 6;
    int s = gstart[g], e = gstart[g + 1];
    float acc = 0.f;
    for (int r = s; r < e; ++r) acc += b2f(hb[(size_t)r * 128 + d]);
    t[d] = (e > s) ? (acc * inv[g] + vn[(size_t)g * 128 + d]) : 0.f;
    __syncthreads();
    float a = b1[d];
    for (int k = 0; k < 128; ++k) a += t[k] * W1[k * 128 + d];
    float ssum = a;
#pragma unroll
    for (int o = 1; o < 64; o <<= 1) ssum += __shfl_xor(ssum, o);
    if (lane == 0) red[w] = ssum;
    __syncthreads();
    float mu = (red[0] + red[1]) * (1.f / 128.f);
    float dv = a - mu;
    float qq = dv * dv;
#pragma unroll
    for (int o = 1; o < 64; o <<= 1) qq += __shfl_xor(qq, o);
    __syncthreads();
    if (lane == 0) red[w] = qq;
    __syncthreads();
    float var = (red[0] + red[1]) * (1.f / 128.f);
    float v = dv * rsqrtf(var + 1e-5f) * lng[d] + lnb[d];
    v = fmaxf(v, 0.f);
    t1[d] = v;
    __syncthreads();
    float o2 = b2[d];
    for (int k = 0; k < 128; ++k) o2 += t1[k] * W2[k * 128 + d];
    out[g * 128 + d] = o2;
}

extern "C" void kernel_launch(void* const* d_in, const int* in_sizes, int n_in,
                              void* d_out, int out_size, void* d_ws, size_t ws_size,
                              hipStream_t stream) {
    const float* x    = (const float*)d_in[0];
    const int*   edge = (const int*)d_in[1];
    const int*   src  = edge;
    const int*   dst  = edge + NEDGES;
    const int*   batch = (const int*)d_in[2];
    const float* nW   = (const float*)d_in[3];
    const float* nb   = (const float*)d_in[4];
    const float* W1s  = (const float*)d_in[5];
    const float* b1s  = (const float*)d_in[6];
    const float* W2s  = (const float*)d_in[7];
    const float* b2s  = (const float*)d_in[8];
    const float* bng  = (const float*)d_in[9];
    const float* bnb  = (const float*)d_in[10];
    const float* vne  = (const float*)d_in[11];
    const float* vW1  = (const float*)d_in[12];
    const float* vb1  = (const float*)d_in[13];
    const float* vW2  = (const float*)d_in[14];
    const float* vb2  = (const float*)d_in[15];
    const float* gW1  = (const float*)d_in[16];
    const float* gb1  = (const float*)d_in[17];
    const float* lng  = (const float*)d_in[18];
    const float* lnb  = (const float*)d_in[19];
    const float* gW2  = (const float*)d_in[20];
    const float* gb2  = (const float*)d_in[21];

    char* ws = (char*)d_ws;
    auto alloc = [&](size_t bytes) { char* p = ws; ws += (bytes + 255) & ~(size_t)255; return p; };
    float*  stats = (float*)alloc(256 * 4);                    // colsum+colsq
    ushort* hb    = (ushort*)alloc((size_t)NPAD * 128 * 2);    // h in bf16
    ushort* mbuf  = (ushort*)alloc((size_t)NPAD * 128 * 2);
    ushort* xb    = (ushort*)alloc((size_t)NPAD * 128 * 2);
    float*  vn    = (float*)alloc((size_t)NGRAPH * 128 * 4);
    ushort* w1t   = (ushort*)alloc((size_t)NLAYER * 256 * 128 * 2);
    ushort* w2t   = (ushort*)alloc((size_t)NLAYER * 128 * 256 * 2);
    float*  inv   = (float*)alloc((size_t)NGRAPH * 4);
    int*    gstart= (int*)alloc((size_t)(NGRAPH + 1) * 4);
    int*    deg   = (int*)alloc((size_t)NNODES * 4);
    int*    rs    = (int*)alloc((size_t)(NNODES + 1) * 4);
    int*    cursor= (int*)alloc((size_t)NNODES * 4);
    int*    csrc  = (int*)alloc((size_t)NEDGES * 4);
    int*    partials = (int*)alloc((size_t)SCAN_NB * 4);
    float*  colsum = stats;
    float*  colsq  = stats + 128;

    float* outN = (float*)d_out;
    float* outG = outN + (size_t)NNODES * 128;

    hipMemsetAsync(stats, 0, 1024, stream);
    hipMemsetAsync(deg, 0, (size_t)NNODES * 4, stream);

    // CSR build (edges constant across layers)
    deg_kernel<<<(NEDGES + 255) / 256, 256, 0, stream>>>(dst, deg);
    scan_part_kernel<<<SCAN_NB, 256, 0, stream>>>(deg, partials);
    scan_top_kernel<<<1, 512, 0, stream>>>(partials);
    scan_blocks_kernel<<<SCAN_NB, 256, 0, stream>>>(deg, partials, rs, cursor);
    csr_scatter_kernel<<<(NEDGES + 255) / 256, 256, 0, stream>>>(src, dst, cursor, csrc);
    gstart_kernel<<<(NGRAPH + 256) / 256, 256, 0, stream>>>(batch, gstart, inv);

    prep_w_kernel<<<(2 * NLAYER * 128 * 256 + 255) / 256, 256, 0, stream>>>(W1s, W2s, w1t, w2t);
    node_embed_kernel<<<(NNODES * 128 + 255) / 256, 256, 0, stream>>>(x, nW, nb, hb);
    vn_init_kernel<<<(NGRAPH * 128 + 255) / 256, 256, 0, stream>>>(vne, vn);

    const int flatNB = (NNODES * 16 + 511) / 512;   // 3125
    for (int i = 0; i < NLAYER; ++i) {
        gin_agg_kernel<<<(NNODES + 15) / 16, 256, 0, stream>>>(hb, rs, csrc, xb);
        fused_mlp_kernel<<<MLP_GRID, 256, 0, stream>>>(
            xb, w1t + (size_t)i * 256 * 128, b1s + i * 256,
            w2t + (size_t)i * 128 * 256, b2s + i * 128, mbuf, colsum, colsq);
        bn_apply_kernel<<<flatNB, 512, 0, stream>>>(
            mbuf, colsum, colsq, bng + i * 128, bnb + i * 128, hb, i > 0 ? 1 : 0);
        vn_update_kernel<<<NGRAPH, 128, 0, stream>>>(hb, gstart, inv, vW1, vb1, vW2, vb2, vn, stats);
        if (i < NLAYER - 1)
            add_vn_kernel<0><<<flatNB, 512, 0, stream>>>(hb, vn, batch, nullptr);
        else
            add_vn_kernel<1><<<flatNB, 512, 0, stream>>>(hb, vn, batch, outN);
    }
    graph_mlp_kernel<<<NGRAPH, 128, 0, stream>>>(hb, gstart, inv, vn, gW1, gb1, lng, lnb, gW2, gb2, outG);
}

// Round 10
// 747.425 us; speedup vs baseline: 1.6198x; 1.1443x over previous
//
#include <hip/hip_runtime.h>
#include <stdint.h>

#define NNODES 100000
#define NEDGES 600000
#define NGRAPH 2048
#define DD 128
#define NLAYER 5
#define NPAD 100096   // 782*128 = 1564*64
#define SCAN_NB 391   // ceil(NNODES/256)
#define NSTAT 32      // stat copies to spread atomic contention

typedef __attribute__((ext_vector_type(8))) __bf16 bf16x8;
typedef __attribute__((ext_vector_type(4))) float f32x4;
typedef __attribute__((ext_vector_type(8))) ushort u16x8;

__device__ __forceinline__ ushort f2b(float f) {
    union { float f; uint32_t u; } v; v.f = f;
    uint32_t r = v.u + 0x7FFFu + ((v.u >> 16) & 1u);
    return (ushort)(r >> 16);
}

__device__ __forceinline__ float b2f(ushort u) {
    union { uint32_t u; float f; } v; v.u = ((uint32_t)u) << 16; return v.f;
}

__device__ __forceinline__ void gload_lds16(const void* g, void* l) {
    __builtin_amdgcn_global_load_lds(
        (const __attribute__((address_space(1))) void*)g,
        (__attribute__((address_space(3))) void*)l, 16, 0, 0);
}

__global__ void prep_w_kernel(const float* __restrict__ W1s, const float* __restrict__ W2s,
                              ushort* __restrict__ w1t, ushort* __restrict__ w2t) {
    int idx = blockIdx.x * 256 + threadIdx.x;
    const int per = 128 * 256;
    if (idx < NLAYER * per) {
        int i = idx / per, rem = idx % per;
        int n = rem >> 7, k = rem & 127;          // w1t[i][n(256)][k(128)] = W1s[i][k][n]
        w1t[idx] = f2b(W1s[(size_t)i * per + k * 256 + n]);
    } else if (idx < 2 * NLAYER * per) {
        int j = idx - NLAYER * per;
        int i = j / per, rem = j % per;
        int n = rem >> 8, k = rem & 255;          // w2t[i][n(128)][k(256)] = W2s[i][k][n]
        w2t[j] = f2b(W2s[(size_t)i * per + k * 128 + n]);
    }
}

__global__ void node_embed_kernel(const float* __restrict__ x, const float* __restrict__ W,
                                  const float* __restrict__ b, ushort* __restrict__ hb) {
    int idx = blockIdx.x * 256 + threadIdx.x;
    if (idx >= NNODES * 128) return;
    int n = idx >> 7, d = idx & 127;
    float v = b[d];
#pragma unroll
    for (int k = 0; k < 9; ++k) v += x[n * 9 + k] * W[k * 128 + d];
    hb[(size_t)n * 128 + d] = f2b(v);
}

__global__ void vn_init_kernel(const float* __restrict__ vne, float* __restrict__ vn) {
    int idx = blockIdx.x * 256 + threadIdx.x;
    if (idx >= NGRAPH * 128) return;
    vn[idx] = vne[idx & 127];
}

// ---------- CSR build (once per call; edges constant across layers) ----------

__global__ void deg_kernel(const int* __restrict__ dst, int* __restrict__ deg) {
    int e = blockIdx.x * 256 + threadIdx.x;
    if (e < NEDGES) atomicAdd(&deg[dst[e]], 1);
}

__global__ void scan_part_kernel(const int* __restrict__ deg, int* __restrict__ partials) {
    int i = blockIdx.x * 256 + threadIdx.x;
    int lane = threadIdx.x & 63, w = threadIdx.x >> 6;
    int v = (i < NNODES) ? deg[i] : 0;
#pragma unroll
    for (int o = 1; o < 64; o <<= 1) v += __shfl_xor(v, o);
    __shared__ int ws[4];
    if (lane == 0) ws[w] = v;
    __syncthreads();
    if (threadIdx.x == 0) partials[blockIdx.x] = ws[0] + ws[1] + ws[2] + ws[3];
}

__global__ __launch_bounds__(512)
void scan_top_kernel(int* __restrict__ partials) {
    __shared__ int s[512];
    int t = threadIdx.x;
    int v = (t < SCAN_NB) ? partials[t] : 0;
    s[t] = v;
    __syncthreads();
#pragma unroll
    for (int o = 1; o < 512; o <<= 1) {
        int n = (t >= o) ? s[t - o] : 0;
        __syncthreads();
        s[t] += n;
        __syncthreads();
    }
    if (t < SCAN_NB) partials[t] = s[t] - v;   // exclusive
}

__global__ void scan_blocks_kernel(const int* __restrict__ deg, const int* __restrict__ partials,
                                   int* __restrict__ rs, int* __restrict__ cursor) {
    int i = blockIdx.x * 256 + threadIdx.x;
    int lane = threadIdx.x & 63, w = threadIdx.x >> 6;
    int v = (i < NNODES) ? deg[i] : 0;
    int x = v;
#pragma unroll
    for (int o = 1; o < 64; o <<= 1) {
        int n = __shfl_up(x, o);
        if (lane >= o) x += n;
    }
    __shared__ int ws[4];
    if (lane == 63) ws[w] = x;
    __syncthreads();
    if (threadIdx.x == 0) {
        int a = 0;
#pragma unroll
        for (int k = 0; k < 4; ++k) { int t = ws[k]; ws[k] = a; a += t; }
    }
    __syncthreads();
    int excl = (x - v) + ws[w] + partials[blockIdx.x];
    if (i < NNODES) { rs[i] = excl; cursor[i] = excl; }
    if (i == 0) rs[NNODES] = NEDGES;
}

__global__ void csr_scatter_kernel(const int* __restrict__ src, const int* __restrict__ dst,
                                   int* __restrict__ cursor, int* __restrict__ csrc) {
    int e = blockIdx.x * 256 + threadIdx.x;
    if (e < NEDGES) {
        int p = atomicAdd(&cursor[dst[e]], 1);
        csrc[p] = src[e];
    }
}

__device__ __forceinline__ int lbound(const int* __restrict__ b, int key) {
    int lo = 0, hi = NNODES;
    while (lo < hi) { int m = (lo + hi) >> 1; if (b[m] < key) lo = m + 1; else hi = m; }
    return lo;
}

// per-graph row range + 1/cnt
__global__ void gstart_kernel(const int* __restrict__ batch, int* __restrict__ gstart,
                              float* __restrict__ inv) {
    int g = blockIdx.x * 256 + threadIdx.x;
    if (g <= NGRAPH)
        gstart[g] = (g == NGRAPH) ? NNODES : lbound(batch, g);
    if (g < NGRAPH) {
        int c = lbound(batch, g + 1) - lbound(batch, g);
        inv[g] = 1.f / (float)(c > 0 ? c : 1);
    }
}

// ---------- GIN aggregation: xb[i] = bf16( h[i] + sum_{j->i} h[j] ), h in bf16 ----------

__global__ __launch_bounds__(256)
void gin_agg_kernel(const ushort* __restrict__ hb, const int* __restrict__ rs,
                    const int* __restrict__ csrc, ushort* __restrict__ xb) {
    int slot = threadIdx.x >> 4;
    int j = threadIdx.x & 15;
    int node = blockIdx.x * 16 + slot;
    if (node >= NNODES) return;
    int s = rs[node], e = rs[node + 1];
    u16x8 v0 = *(const u16x8*)(hb + (size_t)node * 128 + j * 8);
    float a[8];
#pragma unroll
    for (int t = 0; t < 8; ++t) a[t] = b2f(v0[t]);
    for (int k = s; k < e; ++k) {
        int sn = csrc[k];
        u16x8 v = *(const u16x8*)(hb + (size_t)sn * 128 + j * 8);
#pragma unroll
        for (int t = 0; t < 8; ++t) a[t] += b2f(v[t]);
    }
    u16x8 o;
#pragma unroll
    for (int t = 0; t < 8; ++t) o[t] = f2b(a[t]);
    *(u16x8*)(xb + (size_t)node * 128 + j * 8) = o;
}

// ---------- fused MLP v5: v4 + stats spread over NSTAT copies (atomic decontention) ----------
// A: [NPAD][128] bf16. W1: [256][128]. W2: [128][256]. out_b: [NPAD][128] bf16.
// stats layout: copy c at stats[c*256 .. c*256+127]=sum, [+128..+255]=sq
#define MLP_GRID 782   // NPAD/64/2
__global__ __launch_bounds__(256, 2)
void fused_mlp_kernel(const ushort* __restrict__ A, const ushort* __restrict__ W1,
                      const float* __restrict__ b1, const ushort* __restrict__ W2,
                      const float* __restrict__ b2, ushort* __restrict__ out_b,
                      float* __restrict__ stats) {
    __shared__ __align__(16) ushort lA[8192];     // 16KB: [ks:4][q:4][row:64][8]
    __shared__ __align__(16) ushort mid[16384];   // 32KB: [g2:32][row:64][8]
    const int tid = threadIdx.x;
    const int lane = tid & 63, w = tid >> 6;
    const int q = lane >> 4, l16 = lane & 15;
    float* sbase = stats + (blockIdx.x & (NSTAT - 1)) * 256;

    // ---- preload all weight fragments for this wave's n-quadrants into registers ----
    bf16x8 w1f[4][4], w2f[8][2];
#pragma unroll
    for (int ks = 0; ks < 4; ++ks)
#pragma unroll
        for (int ni = 0; ni < 4; ++ni)
            w1f[ks][ni] = *(const bf16x8*)(W1 + (size_t)(w * 64 + ni * 16 + l16) * 128 + ks * 32 + q * 8);
#pragma unroll
    for (int ks = 0; ks < 8; ++ks)
#pragma unroll
        for (int ni = 0; ni < 2; ++ni)
            w2f[ks][ni] = *(const bf16x8*)(W2 + (size_t)(w * 32 + ni * 16 + l16) * 256 + ks * 32 + q * 8);

    // stage tile 0
    {
        int rb = blockIdx.x * 128;
#pragma unroll
        for (int p = 0; p < 4; ++p)
            gload_lds16(A + (size_t)(rb + lane) * 128 + p * 32 + w * 8,
                        &lA[(size_t)(p * 256 + w * 64 + lane) * 8]);
    }

    for (int tt = 0; tt < 2; ++tt) {
        const int rb = blockIdx.x * 128 + tt * 64;
        __syncthreads();   // drains vmcnt (stage done) + orders mid reuse

        // ---- phase 1: C1[64][256] = A@W1 from LDS x regs ----
        f32x4 acc1[4][4] = {};
#pragma unroll
        for (int ks = 0; ks < 4; ++ks) {
            bf16x8 af[4];
#pragma unroll
            for (int mi = 0; mi < 4; ++mi)
                af[mi] = *(const bf16x8*)&lA[ks * 2048 + q * 512 + (mi * 16 + l16) * 8];
#pragma unroll
            for (int mi = 0; mi < 4; ++mi)
#pragma unroll
                for (int ni = 0; ni < 4; ++ni)
                    acc1[mi][ni] = __builtin_amdgcn_mfma_f32_16x16x32_bf16(af[mi], w1f[ks][ni], acc1[mi][ni], 0, 0, 0);
        }

        // relu(C1+b1) -> bf16 -> mid [g2][row][8]
#pragma unroll
        for (int ni = 0; ni < 4; ++ni) {
            int col = w * 64 + ni * 16 + l16;
            float bs = b1[col];
            int g2 = col >> 3, jj = col & 7;
#pragma unroll
            for (int mi = 0; mi < 4; ++mi) {
                int rowb = mi * 16 + q * 4;
#pragma unroll
                for (int r = 0; r < 4; ++r) {
                    float v = acc1[mi][ni][r] + bs;
                    v = v > 0.f ? v : 0.f;
                    mid[g2 * 512 + (rowb + r) * 8 + jj] = f2b(v);
                }
            }
        }
        __syncthreads();   // mid visible; lA reads done -> safe to restage

        // stage next tile (overlaps phase 2)
        if (tt == 0) {
            int rb2 = blockIdx.x * 128 + 64;
#pragma unroll
            for (int p = 0; p < 4; ++p)
                gload_lds16(A + (size_t)(rb2 + lane) * 128 + p * 32 + w * 8,
                            &lA[(size_t)(p * 256 + w * 64 + lane) * 8]);
        }

        // ---- phase 2: C2[64][128] = mid@W2 + b2 ----
        f32x4 acc2[4][2] = {};
#pragma unroll
        for (int ks = 0; ks < 8; ++ks) {
            bf16x8 af[4];
#pragma unroll
            for (int mi = 0; mi < 4; ++mi)
                af[mi] = *(const bf16x8*)&mid[(ks * 4 + q) * 512 + (mi * 16 + l16) * 8];
#pragma unroll
            for (int mi = 0; mi < 4; ++mi)
#pragma unroll
                for (int ni = 0; ni < 2; ++ni)
                    acc2[mi][ni] = __builtin_amdgcn_mfma_f32_16x16x32_bf16(af[mi], w2f[ks][ni], acc2[mi][ni], 0, 0, 0);
        }

#pragma unroll
        for (int ni = 0; ni < 2; ++ni) {
            int col = w * 32 + ni * 16 + l16;
            float bs = b2[col];
            float s = 0.f, sq = 0.f;
#pragma unroll
            for (int mi = 0; mi < 4; ++mi) {
                int row = rb + mi * 16 + q * 4;
#pragma unroll
                for (int r = 0; r < 4; ++r) {
                    float v = acc2[mi][ni][r] + bs;
                    out_b[(size_t)(row + r) * 128 + col] = f2b(v);
                    if (row + r < NNODES) { s += v; sq += v * v; }
                }
            }
            s  += __shfl_xor(s, 16);  s  += __shfl_xor(s, 32);
            sq += __shfl_xor(sq, 16); sq += __shfl_xor(sq, 32);
            if (lane < 16) {
                atomicAdd(&sbase[col], s);
                atomicAdd(&sbase[128 + col], sq);
            }
        }
    }
}

// ---------- BN finalize (reduce NSTAT copies) + apply + residual; flat, no contended atomics ----------
__global__ __launch_bounds__(512)
void bn_apply_kernel(const ushort* __restrict__ m, const float* __restrict__ stats,
                     const float* __restrict__ bng, const float* __restrict__ bnb,
                     ushort* __restrict__ hb, int resid) {
    __shared__ float sC[128], sS[128];
    if (threadIdx.x < 128) {
        int d = threadIdx.x;
        float sum = 0.f, sq = 0.f;
#pragma unroll
        for (int c = 0; c < NSTAT; ++c) {
            sum += stats[c * 256 + d];
            sq  += stats[c * 256 + 128 + d];
        }
        float mu = sum * (1.f / NNODES);
        float var = sq * (1.f / NNODES) - mu * mu;
        var = var < 0.f ? 0.f : var;
        float sc = bng[d] * rsqrtf(var + 1e-5f);
        sC[d] = sc;
        sS[d] = bnb[d] - mu * sc;
    }
    __syncthreads();
    int t = blockIdx.x * 512 + threadIdx.x;   // (row, j16) units
    if (t >= NNODES * 16) return;
    int row = t >> 4, j = t & 15;
    u16x8 mu8 = *(const u16x8*)(m + (size_t)row * 128 + j * 8);
    float wv[8];
#pragma unroll
    for (int k = 0; k < 8; ++k)
        wv[k] = fmaxf(b2f(mu8[k]) * sC[j * 8 + k] + sS[j * 8 + k], 0.f);
    if (resid) {
        u16x8 hp = *(const u16x8*)(hb + (size_t)row * 128 + j * 8);
#pragma unroll
        for (int k = 0; k < 8; ++k) wv[k] += b2f(hp[k]);
    }
    u16x8 o;
#pragma unroll
    for (int k = 0; k < 8; ++k) o[k] = f2b(wv[k]);
    *(u16x8*)(hb + (size_t)row * 128 + j * 8) = o;
}

// ---------- vn update with in-kernel per-graph pooling; zeroes stat copies for next layer ----------
__global__ void vn_update_kernel(const ushort* __restrict__ hb, const int* __restrict__ gstart,
                                 const float* __restrict__ inv,
                                 const float* __restrict__ W1, const float* __restrict__ b1,
                                 const float* __restrict__ W2, const float* __restrict__ b2,
                                 float* __restrict__ vn, float* __restrict__ stats) {
    __shared__ float t[128], t1[128];
    int g = blockIdx.x, d = threadIdx.x;
    int s = gstart[g], e = gstart[g + 1];
    float acc = 0.f;
    for (int r = s; r < e; ++r) acc += b2f(hb[(size_t)r * 128 + d]);
    t[d] = acc * inv[g];
    if (g < NSTAT) { stats[g * 256 + d] = 0.f; stats[g * 256 + 128 + d] = 0.f; }
    __syncthreads();
    float a = b1[d];
    for (int k = 0; k < 128; ++k) a += t[k] * W1[k * 128 + d];
    t1[d] = fmaxf(a, 0.f);
    __syncthreads();
    float o = b2[d];
    for (int k = 0; k < 128; ++k) o += t1[k] * W2[k * 128 + d];
    vn[g * 128 + d] += o;
}

// ---------- h += vn[batch]; flat. FINAL: write f32 outN instead ----------
template<int FINAL>
__global__ __launch_bounds__(512)
void add_vn_kernel(ushort* __restrict__ hb, const float* __restrict__ vn,
                   const int* __restrict__ batch, float* __restrict__ outN) {
    int t = blockIdx.x * 512 + threadIdx.x;
    if (t >= NNODES * 16) return;
    int row = t >> 4, j = t & 15;
    int g = batch[row];
    float4 v0 = ((const float4*)(vn + (size_t)g * 128))[j * 2];
    float4 v1 = ((const float4*)(vn + (size_t)g * 128))[j * 2 + 1];
    u16x8 hv = *(const u16x8*)(hb + (size_t)row * 128 + j * 8);
    float wv[8];
    wv[0] = b2f(hv[0]) + v0.x; wv[1] = b2f(hv[1]) + v0.y;
    wv[2] = b2f(hv[2]) + v0.z; wv[3] = b2f(hv[3]) + v0.w;
    wv[4] = b2f(hv[4]) + v1.x; wv[5] = b2f(hv[5]) + v1.y;
    wv[6] = b2f(hv[6]) + v1.z; wv[7] = b2f(hv[7]) + v1.w;
    if (FINAL) {
        float4* op = (float4*)(outN + (size_t)row * 128 + j * 8);
        op[0] = make_float4(wv[0], wv[1], wv[2], wv[3]);
        op[1] = make_float4(wv[4], wv[5], wv[6], wv[7]);
    } else {
        u16x8 o;
#pragma unroll
        for (int k = 0; k < 8; ++k) o[k] = f2b(wv[k]);
        *(u16x8*)(hb + (size_t)row * 128 + j * 8) = o;
    }
}

// ---------- graph MLP with in-kernel final pooling (pool(hb)+vn == pool(outN)) ----------
__global__ void graph_mlp_kernel(const ushort* __restrict__ hb, const int* __restrict__ gstart,
                                 const float* __restrict__ inv, const float* __restrict__ vn,
                                 const float* __restrict__ W1, const float* __restrict__ b1,
                                 const float* __restrict__ lng, const float* __restrict__ lnb,
                                 const float* __restrict__ W2, const float* __restrict__ b2,
                                 float* __restrict__ out) {
    __shared__ float t[128], t1[128], red[2];
    int g = blockIdx.x, d = threadIdx.x;
    int lane = d & 63, w = d >> 6;
    int s = gstart[g], e = gstart[g + 1];
    float acc = 0.f;
    for (int r = s; r < e; ++r) acc += b2f(hb[(size_t)r * 128 + d]);
    t[d] = (e > s) ? (acc * inv[g] + vn[(size_t)g * 128 + d]) : 0.f;
    __syncthreads();
    float a = b1[d];
    for (int k = 0; k < 128; ++k) a += t[k] * W1[k * 128 + d];
    float ssum = a;
#pragma unroll
    for (int o = 1; o < 64; o <<= 1) ssum += __shfl_xor(ssum, o);
    if (lane == 0) red[w] = ssum;
    __syncthreads();
    float mu = (red[0] + red[1]) * (1.f / 128.f);
    float dv = a - mu;
    float qq = dv * dv;
#pragma unroll
    for (int o = 1; o < 64; o <<= 1) qq += __shfl_xor(qq, o);
    __syncthreads();
    if (lane == 0) red[w] = qq;
    __syncthreads();
    float var = (red[0] + red[1]) * (1.f / 128.f);
    float v = dv * rsqrtf(var + 1e-5f) * lng[d] + lnb[d];
    v = fmaxf(v, 0.f);
    t1[d] = v;
    __syncthreads();
    float o2 = b2[d];
    for (int k = 0; k < 128; ++k) o2 += t1[k] * W2[k * 128 + d];
    out[g * 128 + d] = o2;
}

extern "C" void kernel_launch(void* const* d_in, const int* in_sizes, int n_in,
                              void* d_out, int out_size, void* d_ws, size_t ws_size,
                              hipStream_t stream) {
    const float* x    = (const float*)d_in[0];
    const int*   edge = (const int*)d_in[1];
    const int*   src  = edge;
    const int*   dst  = edge + NEDGES;
    const int*   batch = (const int*)d_in[2];
    const float* nW   = (const float*)d_in[3];
    const float* nb   = (const float*)d_in[4];
    const float* W1s  = (const float*)d_in[5];
    const float* b1s  = (const float*)d_in[6];
    const float* W2s  = (const float*)d_in[7];
    const float* b2s  = (const float*)d_in[8];
    const float* bng  = (const float*)d_in[9];
    const float* bnb  = (const float*)d_in[10];
    const float* vne  = (const float*)d_in[11];
    const float* vW1  = (const float*)d_in[12];
    const float* vb1  = (const float*)d_in[13];
    const float* vW2  = (const float*)d_in[14];
    const float* vb2  = (const float*)d_in[15];
    const float* gW1  = (const float*)d_in[16];
    const float* gb1  = (const float*)d_in[17];
    const float* lng  = (const float*)d_in[18];
    const float* lnb  = (const float*)d_in[19];
    const float* gW2  = (const float*)d_in[20];
    const float* gb2  = (const float*)d_in[21];

    char* ws = (char*)d_ws;
    auto alloc = [&](size_t bytes) { char* p = ws; ws += (bytes + 255) & ~(size_t)255; return p; };
    float*  stats = (float*)alloc((size_t)NSTAT * 256 * 4);    // 32 copies of colsum+colsq
    ushort* hb    = (ushort*)alloc((size_t)NPAD * 128 * 2);    // h in bf16
    ushort* mbuf  = (ushort*)alloc((size_t)NPAD * 128 * 2);
    ushort* xb    = (ushort*)alloc((size_t)NPAD * 128 * 2);
    float*  vn    = (float*)alloc((size_t)NGRAPH * 128 * 4);
    ushort* w1t   = (ushort*)alloc((size_t)NLAYER * 256 * 128 * 2);
    ushort* w2t   = (ushort*)alloc((size_t)NLAYER * 128 * 256 * 2);
    float*  inv   = (float*)alloc((size_t)NGRAPH * 4);
    int*    gstart= (int*)alloc((size_t)(NGRAPH + 1) * 4);
    int*    deg   = (int*)alloc((size_t)NNODES * 4);
    int*    rs    = (int*)alloc((size_t)(NNODES + 1) * 4);
    int*    cursor= (int*)alloc((size_t)NNODES * 4);
    int*    csrc  = (int*)alloc((size_t)NEDGES * 4);
    int*    partials = (int*)alloc((size_t)SCAN_NB * 4);

    float* outN = (float*)d_out;
    float* outG = outN + (size_t)NNODES * 128;

    hipMemsetAsync(stats, 0, (size_t)NSTAT * 256 * 4, stream);
    hipMemsetAsync(deg, 0, (size_t)NNODES * 4, stream);

    // CSR build (edges constant across layers)
    deg_kernel<<<(NEDGES + 255) / 256, 256, 0, stream>>>(dst, deg);
    scan_part_kernel<<<SCAN_NB, 256, 0, stream>>>(deg, partials);
    scan_top_kernel<<<1, 512, 0, stream>>>(partials);
    scan_blocks_kernel<<<SCAN_NB, 256, 0, stream>>>(deg, partials, rs, cursor);
    csr_scatter_kernel<<<(NEDGES + 255) / 256, 256, 0, stream>>>(src, dst, cursor, csrc);
    gstart_kernel<<<(NGRAPH + 256) / 256, 256, 0, stream>>>(batch, gstart, inv);

    prep_w_kernel<<<(2 * NLAYER * 128 * 256 + 255) / 256, 256, 0, stream>>>(W1s, W2s, w1t, w2t);
    node_embed_kernel<<<(NNODES * 128 + 255) / 256, 256, 0, stream>>>(x, nW, nb, hb);
    vn_init_kernel<<<(NGRAPH * 128 + 255) / 256, 256, 0, stream>>>(vne, vn);

    const int flatNB = (NNODES * 16 + 511) / 512;   // 3125
    for (int i = 0; i < NLAYER; ++i) {
        gin_agg_kernel<<<(NNODES + 15) / 16, 256, 0, stream>>>(hb, rs, csrc, xb);
        fused_mlp_kernel<<<MLP_GRID, 256, 0, stream>>>(
            xb, w1t + (size_t)i * 256 * 128, b1s + i * 256,
            w2t + (size_t)i * 128 * 256, b2s + i * 128, mbuf, stats);
        bn_apply_kernel<<<flatNB, 512, 0, stream>>>(
            mbuf, stats, bng + i * 128, bnb + i * 128, hb, i > 0 ? 1 : 0);
        vn_update_kernel<<<NGRAPH, 128, 0, stream>>>(hb, gstart, inv, vW1, vb1, vW2, vb2, vn, stats);
        if (i < NLAYER - 1)
            add_vn_kernel<0><<<flatNB, 512, 0, stream>>>(hb, vn, batch, nullptr);
        else
            add_vn_kernel<1><<<flatNB, 512, 0, stream>>>(hb, vn, batch, outN);
    }
    graph_mlp_kernel<<<NGRAPH, 128, 0, stream>>>(hb, gstart, inv, vn, gW1, gb1, lng, lnb, gW2, gb2, outG);
}

// Round 11
// 697.266 us; speedup vs baseline: 1.7364x; 1.0719x over previous
//
#include <hip/hip_runtime.h>
#include <stdint.h>

#define NNODES 100000
#define NEDGES 600000
#define NGRAPH 2048
#define DD 128
#define NLAYER 5
#define NPAD 100096   // 782*128 = 1564*64 = 391*256
#define SCAN_NB 391   // ceil(NNODES/256)
#define NSTAT 32      // stat copies to spread atomic contention

typedef __attribute__((ext_vector_type(8))) __bf16 bf16x8;
typedef __attribute__((ext_vector_type(4))) float f32x4;
typedef __attribute__((ext_vector_type(8))) ushort u16x8;

__device__ __forceinline__ ushort f2b(float f) {
    union { float f; uint32_t u; } v; v.f = f;
    uint32_t r = v.u + 0x7FFFu + ((v.u >> 16) & 1u);
    return (ushort)(r >> 16);
}

__device__ __forceinline__ float b2f(ushort u) {
    union { uint32_t u; float f; } v; v.u = ((uint32_t)u) << 16; return v.f;
}

__device__ __forceinline__ void gload_lds16(const void* g, void* l) {
    __builtin_amdgcn_global_load_lds(
        (const __attribute__((address_space(1))) void*)g,
        (__attribute__((address_space(3))) void*)l, 16, 0, 0);
}

__global__ void prep_w_kernel(const float* __restrict__ W1s, const float* __restrict__ W2s,
                              ushort* __restrict__ w1t, ushort* __restrict__ w2t) {
    int idx = blockIdx.x * 256 + threadIdx.x;
    const int per = 128 * 256;
    if (idx < NLAYER * per) {
        int i = idx / per, rem = idx % per;
        int n = rem >> 7, k = rem & 127;          // w1t[i][n(256)][k(128)] = W1s[i][k][n]
        w1t[idx] = f2b(W1s[(size_t)i * per + k * 256 + n]);
    } else if (idx < 2 * NLAYER * per) {
        int j = idx - NLAYER * per;
        int i = j / per, rem = j % per;
        int n = rem >> 8, k = rem & 255;          // w2t[i][n(128)][k(256)] = W2s[i][k][n]
        w2t[j] = f2b(W2s[(size_t)i * per + k * 128 + n]);
    }
}

// node embedding + vn init in one launch
__global__ void node_embed_kernel(const float* __restrict__ x, const float* __restrict__ W,
                                  const float* __restrict__ b, ushort* __restrict__ hb,
                                  const float* __restrict__ vne, float* __restrict__ vn) {
    int idx = blockIdx.x * 256 + threadIdx.x;
    if (idx < NNODES * 128) {
        int n = idx >> 7, d = idx & 127;
        float v = b[d];
#pragma unroll
        for (int k = 0; k < 9; ++k) v += x[n * 9 + k] * W[k * 128 + d];
        hb[(size_t)n * 128 + d] = f2b(v);
    } else if (idx < NNODES * 128 + NGRAPH * 128) {
        int r = idx - NNODES * 128;
        vn[r] = vne[r & 127];
    }
}

// ---------- CSR build (once per call; edges constant across layers) ----------

__global__ void deg_kernel(const int* __restrict__ dst, int* __restrict__ deg) {
    int e = blockIdx.x * 256 + threadIdx.x;
    if (e < NEDGES) atomicAdd(&deg[dst[e]], 1);
}

__global__ void scan_part_kernel(const int* __restrict__ deg, int* __restrict__ partials) {
    int i = blockIdx.x * 256 + threadIdx.x;
    int lane = threadIdx.x & 63, w = threadIdx.x >> 6;
    int v = (i < NNODES) ? deg[i] : 0;
#pragma unroll
    for (int o = 1; o < 64; o <<= 1) v += __shfl_xor(v, o);
    __shared__ int ws[4];
    if (lane == 0) ws[w] = v;
    __syncthreads();
    if (threadIdx.x == 0) partials[blockIdx.x] = ws[0] + ws[1] + ws[2] + ws[3];
}

__global__ __launch_bounds__(512)
void scan_top_kernel(int* __restrict__ partials) {
    __shared__ int s[512];
    int t = threadIdx.x;
    int v = (t < SCAN_NB) ? partials[t] : 0;
    s[t] = v;
    __syncthreads();
#pragma unroll
    for (int o = 1; o < 512; o <<= 1) {
        int n = (t >= o) ? s[t - o] : 0;
        __syncthreads();
        s[t] += n;
        __syncthreads();
    }
    if (t < SCAN_NB) partials[t] = s[t] - v;   // exclusive
}

__global__ void scan_blocks_kernel(const int* __restrict__ deg, const int* __restrict__ partials,
                                   int* __restrict__ rs, int* __restrict__ cursor) {
    int i = blockIdx.x * 256 + threadIdx.x;
    int lane = threadIdx.x & 63, w = threadIdx.x >> 6;
    int v = (i < NNODES) ? deg[i] : 0;
    int x = v;
#pragma unroll
    for (int o = 1; o < 64; o <<= 1) {
        int n = __shfl_up(x, o);
        if (lane >= o) x += n;
    }
    __shared__ int ws[4];
    if (lane == 63) ws[w] = x;
    __syncthreads();
    if (threadIdx.x == 0) {
        int a = 0;
#pragma unroll
        for (int k = 0; k < 4; ++k) { int t = ws[k]; ws[k] = a; a += t; }
    }
    __syncthreads();
    int excl = (x - v) + ws[w] + partials[blockIdx.x];
    if (i < NNODES) { rs[i] = excl; cursor[i] = excl; }
    if (i == 0) rs[NNODES] = NEDGES;
}

__global__ void csr_scatter_kernel(const int* __restrict__ src, const int* __restrict__ dst,
                                   int* __restrict__ cursor, int* __restrict__ csrc) {
    int e = blockIdx.x * 256 + threadIdx.x;
    if (e < NEDGES) {
        int p = atomicAdd(&cursor[dst[e]], 1);
        csrc[p] = src[e];
    }
}

__device__ __forceinline__ int lbound(const int* __restrict__ b, int key) {
    int lo = 0, hi = NNODES;
    while (lo < hi) { int m = (lo + hi) >> 1; if (b[m] < key) lo = m + 1; else hi = m; }
    return lo;
}

// per-graph row range + 1/cnt
__global__ void gstart_kernel(const int* __restrict__ batch, int* __restrict__ gstart,
                              float* __restrict__ inv) {
    int g = blockIdx.x * 256 + threadIdx.x;
    if (g <= NGRAPH)
        gstart[g] = (g == NGRAPH) ? NNODES : lbound(batch, g);
    if (g < NGRAPH) {
        int c = lbound(batch, g + 1) - lbound(batch, g);
        inv[g] = 1.f / (float)(c > 0 ? c : 1);
    }
}

// ---------- GIN aggregation: xb[i] = bf16( h[i] + sum_{j->i} h[j] ), 2-way unrolled ----------

__global__ __launch_bounds__(256)
void gin_agg_kernel(const ushort* __restrict__ hb, const int* __restrict__ rs,
                    const int* __restrict__ csrc, ushort* __restrict__ xb) {
    int slot = threadIdx.x >> 4;
    int j = threadIdx.x & 15;
    int node = blockIdx.x * 16 + slot;
    if (node >= NNODES) return;
    int s = rs[node], e = rs[node + 1];
    u16x8 v0 = *(const u16x8*)(hb + (size_t)node * 128 + j * 8);
    float a[8], b[8];
#pragma unroll
    for (int t = 0; t < 8; ++t) { a[t] = b2f(v0[t]); b[t] = 0.f; }
    int k = s;
    for (; k + 1 < e; k += 2) {
        int s0 = csrc[k], s1 = csrc[k + 1];
        u16x8 va = *(const u16x8*)(hb + (size_t)s0 * 128 + j * 8);
        u16x8 vb = *(const u16x8*)(hb + (size_t)s1 * 128 + j * 8);
#pragma unroll
        for (int t = 0; t < 8; ++t) { a[t] += b2f(va[t]); b[t] += b2f(vb[t]); }
    }
    if (k < e) {
        int s0 = csrc[k];
        u16x8 va = *(const u16x8*)(hb + (size_t)s0 * 128 + j * 8);
#pragma unroll
        for (int t = 0; t < 8; ++t) a[t] += b2f(va[t]);
    }
    u16x8 o;
#pragma unroll
    for (int t = 0; t < 8; ++t) o[t] = f2b(a[t] + b[t]);
    *(u16x8*)(xb + (size_t)node * 128 + j * 8) = o;
}

// ---------- fused MLP v6: weights in regs, 4 tiles/block, async A pipeline, spread stats ----------
// A: [NPAD][128] bf16. W1: [256][128]. W2: [128][256]. out_b: [NPAD][128] bf16.
#define MLP_TILES 4
#define MLP_GRID 391   // NPAD/64/MLP_TILES
__global__ __launch_bounds__(256, 2)
void fused_mlp_kernel(const ushort* __restrict__ A, const ushort* __restrict__ W1,
                      const float* __restrict__ b1, const ushort* __restrict__ W2,
                      const float* __restrict__ b2, ushort* __restrict__ out_b,
                      float* __restrict__ stats) {
    __shared__ __align__(16) ushort lA[8192];     // 16KB: [ks:4][q:4][row:64][8]
    __shared__ __align__(16) ushort mid[16384];   // 32KB: [g2:32][row:64][8]
    const int tid = threadIdx.x;
    const int lane = tid & 63, w = tid >> 6;
    const int q = lane >> 4, l16 = lane & 15;
    float* sbase = stats + (blockIdx.x & (NSTAT - 1)) * 256;

    // preload all weight fragments for this wave's n-quadrants into registers
    bf16x8 w1f[4][4], w2f[8][2];
#pragma unroll
    for (int ks = 0; ks < 4; ++ks)
#pragma unroll
        for (int ni = 0; ni < 4; ++ni)
            w1f[ks][ni] = *(const bf16x8*)(W1 + (size_t)(w * 64 + ni * 16 + l16) * 128 + ks * 32 + q * 8);
#pragma unroll
    for (int ks = 0; ks < 8; ++ks)
#pragma unroll
        for (int ni = 0; ni < 2; ++ni)
            w2f[ks][ni] = *(const bf16x8*)(W2 + (size_t)(w * 32 + ni * 16 + l16) * 256 + ks * 32 + q * 8);

    // stage tile 0
    {
        int rb = blockIdx.x * (64 * MLP_TILES);
#pragma unroll
        for (int p = 0; p < 4; ++p)
            gload_lds16(A + (size_t)(rb + lane) * 128 + p * 32 + w * 8,
                        &lA[(size_t)(p * 256 + w * 64 + lane) * 8]);
    }

    for (int tt = 0; tt < MLP_TILES; ++tt) {
        const int rb = blockIdx.x * (64 * MLP_TILES) + tt * 64;
        __syncthreads();   // drains vmcnt (stage done) + orders mid reuse

        // ---- phase 1: C1[64][256] = A@W1 from LDS x regs ----
        f32x4 acc1[4][4] = {};
#pragma unroll
        for (int ks = 0; ks < 4; ++ks) {
            bf16x8 af[4];
#pragma unroll
            for (int mi = 0; mi < 4; ++mi)
                af[mi] = *(const bf16x8*)&lA[ks * 2048 + q * 512 + (mi * 16 + l16) * 8];
#pragma unroll
            for (int mi = 0; mi < 4; ++mi)
#pragma unroll
                for (int ni = 0; ni < 4; ++ni)
                    acc1[mi][ni] = __builtin_amdgcn_mfma_f32_16x16x32_bf16(af[mi], w1f[ks][ni], acc1[mi][ni], 0, 0, 0);
        }

        // relu(C1+b1) -> bf16 -> mid [g2][row][8]
#pragma unroll
        for (int ni = 0; ni < 4; ++ni) {
            int col = w * 64 + ni * 16 + l16;
            float bs = b1[col];
            int g2 = col >> 3, jj = col & 7;
#pragma unroll
            for (int mi = 0; mi < 4; ++mi) {
                int rowb = mi * 16 + q * 4;
#pragma unroll
                for (int r = 0; r < 4; ++r) {
                    float v = acc1[mi][ni][r] + bs;
                    v = v > 0.f ? v : 0.f;
                    mid[g2 * 512 + (rowb + r) * 8 + jj] = f2b(v);
                }
            }
        }
        __syncthreads();   // mid visible; lA reads done -> safe to restage

        // stage next tile (overlaps phase 2)
        if (tt + 1 < MLP_TILES) {
            int rb2 = rb + 64;
#pragma unroll
            for (int p = 0; p < 4; ++p)
                gload_lds16(A + (size_t)(rb2 + lane) * 128 + p * 32 + w * 8,
                            &lA[(size_t)(p * 256 + w * 64 + lane) * 8]);
        }

        // ---- phase 2: C2[64][128] = mid@W2 + b2 ----
        f32x4 acc2[4][2] = {};
#pragma unroll
        for (int ks = 0; ks < 8; ++ks) {
            bf16x8 af[4];
#pragma unroll
            for (int mi = 0; mi < 4; ++mi)
                af[mi] = *(const bf16x8*)&mid[(ks * 4 + q) * 512 + (mi * 16 + l16) * 8];
#pragma unroll
            for (int mi = 0; mi < 4; ++mi)
#pragma unroll
                for (int ni = 0; ni < 2; ++ni)
                    acc2[mi][ni] = __builtin_amdgcn_mfma_f32_16x16x32_bf16(af[mi], w2f[ks][ni], acc2[mi][ni], 0, 0, 0);
        }

#pragma unroll
        for (int ni = 0; ni < 2; ++ni) {
            int col = w * 32 + ni * 16 + l16;
            float bs = b2[col];
            float s = 0.f, sq = 0.f;
#pragma unroll
            for (int mi = 0; mi < 4; ++mi) {
                int row = rb + mi * 16 + q * 4;
#pragma unroll
                for (int r = 0; r < 4; ++r) {
                    float v = acc2[mi][ni][r] + bs;
                    out_b[(size_t)(row + r) * 128 + col] = f2b(v);
                    if (row + r < NNODES) { s += v; sq += v * v; }
                }
            }
            s  += __shfl_xor(s, 16);  s  += __shfl_xor(s, 32);
            sq += __shfl_xor(sq, 16); sq += __shfl_xor(sq, 32);
            if (lane < 16) {
                atomicAdd(&sbase[col], s);
                atomicAdd(&sbase[128 + col], sq);
            }
        }
    }
}

// ---------- BN finalize (reduce NSTAT copies) + apply + residual; flat ----------
__global__ __launch_bounds__(512)
void bn_apply_kernel(const ushort* __restrict__ m, const float* __restrict__ stats,
                     const float* __restrict__ bng, const float* __restrict__ bnb,
                     ushort* __restrict__ hb, int resid) {
    __shared__ float sC[128], sS[128];
    if (threadIdx.x < 128) {
        int d = threadIdx.x;
        float sum = 0.f, sq = 0.f;
#pragma unroll
        for (int c = 0; c < NSTAT; ++c) {
            sum += stats[c * 256 + d];
            sq  += stats[c * 256 + 128 + d];
        }
        float mu = sum * (1.f / NNODES);
        float var = sq * (1.f / NNODES) - mu * mu;
        var = var < 0.f ? 0.f : var;
        float sc = bng[d] * rsqrtf(var + 1e-5f);
        sC[d] = sc;
        sS[d] = bnb[d] - mu * sc;
    }
    __syncthreads();
    int t = blockIdx.x * 512 + threadIdx.x;   // (row, j16) units
    if (t >= NNODES * 16) return;
    int row = t >> 4, j = t & 15;
    u16x8 mu8 = *(const u16x8*)(m + (size_t)row * 128 + j * 8);
    float wv[8];
#pragma unroll
    for (int k = 0; k < 8; ++k)
        wv[k] = fmaxf(b2f(mu8[k]) * sC[j * 8 + k] + sS[j * 8 + k], 0.f);
    if (resid) {
        u16x8 hp = *(const u16x8*)(hb + (size_t)row * 128 + j * 8);
#pragma unroll
        for (int k = 0; k < 8; ++k) wv[k] += b2f(hp[k]);
    }
    u16x8 o;
#pragma unroll
    for (int k = 0; k < 8; ++k) o[k] = f2b(wv[k]);
    *(u16x8*)(hb + (size_t)row * 128 + j * 8) = o;
}

// ---------- vn update with in-kernel per-graph pooling; zeroes stat copies for next layer ----------
__global__ void vn_update_kernel(const ushort* __restrict__ hb, const int* __restrict__ gstart,
                                 const float* __restrict__ inv,
                                 const float* __restrict__ W1, const float* __restrict__ b1,
                                 const float* __restrict__ W2, const float* __restrict__ b2,
                                 float* __restrict__ vn, float* __restrict__ stats) {
    __shared__ float t[128], t1[128];
    int g = blockIdx.x, d = threadIdx.x;
    int s = gstart[g], e = gstart[g + 1];
    float acc = 0.f;
    for (int r = s; r < e; ++r) acc += b2f(hb[(size_t)r * 128 + d]);
    t[d] = acc * inv[g];
    if (g < NSTAT) { stats[g * 256 + d] = 0.f; stats[g * 256 + 128 + d] = 0.f; }
    __syncthreads();
    float a = b1[d];
    for (int k = 0; k < 128; ++k) a += t[k] * W1[k * 128 + d];
    t1[d] = fmaxf(a, 0.f);
    __syncthreads();
    float o = b2[d];
    for (int k = 0; k < 128; ++k) o += t1[k] * W2[k * 128 + d];
    vn[g * 128 + d] += o;
}

// ---------- h += vn[batch]; flat. FINAL: write f32 outN instead ----------
template<int FINAL>
__global__ __launch_bounds__(512)
void add_vn_kernel(ushort* __restrict__ hb, const float* __restrict__ vn,
                   const int* __restrict__ batch, float* __restrict__ outN) {
    int t = blockIdx.x * 512 + threadIdx.x;
    if (t >= NNODES * 16) return;
    int row = t >> 4, j = t & 15;
    int g = batch[row];
    float4 v0 = ((const float4*)(vn + (size_t)g * 128))[j * 2];
    float4 v1 = ((const float4*)(vn + (size_t)g * 128))[j * 2 + 1];
    u16x8 hv = *(const u16x8*)(hb + (size_t)row * 128 + j * 8);
    float wv[8];
    wv[0] = b2f(hv[0]) + v0.x; wv[1] = b2f(hv[1]) + v0.y;
    wv[2] = b2f(hv[2]) + v0.z; wv[3] = b2f(hv[3]) + v0.w;
    wv[4] = b2f(hv[4]) + v1.x; wv[5] = b2f(hv[5]) + v1.y;
    wv[6] = b2f(hv[6]) + v1.z; wv[7] = b2f(hv[7]) + v1.w;
    if (FINAL) {
        float4* op = (float4*)(outN + (size_t)row * 128 + j * 8);
        op[0] = make_float4(wv[0], wv[1], wv[2], wv[3]);
        op[1] = make_float4(wv[4], wv[5], wv[6], wv[7]);
    } else {
        u16x8 o;
#pragma unroll
        for (int k = 0; k < 8; ++k) o[k] = f2b(wv[k]);
        *(u16x8*)(hb + (size_t)row * 128 + j * 8) = o;
    }
}

// ---------- graph MLP with in-kernel final pooling (pool(hb)+vn == pool(outN)) ----------
__global__ void graph_mlp_kernel(const ushort* __restrict__ hb, const int* __restrict__ gstart,
                                 const float* __restrict__ inv, const float* __restrict__ vn,
                                 const float* __restrict__ W1, const float* __restrict__ b1,
                                 const float* __restrict__ lng, const float* __restrict__ lnb,
                                 const float* __restrict__ W2, const float* __restrict__ b2,
                                 float* __restrict__ out) {
    __shared__ float t[128], t1[128], red[2];
    int g = blockIdx.x, d = threadIdx.x;
    int lane = d & 63, w = d >> 6;
    int s = gstart[g], e = gstart[g + 1];
    float acc = 0.f;
    for (int r = s; r < e; ++r) acc += b2f(hb[(size_t)r * 128 + d]);
    t[d] = (e > s) ? (acc * inv[g] + vn[(size_t)g * 128 + d]) : 0.f;
    __syncthreads();
    float a = b1[d];
    for (int k = 0; k < 128; ++k) a += t[k] * W1[k * 128 + d];
    float ssum = a;
#pragma unroll
    for (int o = 1; o < 64; o <<= 1) ssum += __shfl_xor(ssum, o);
    if (lane == 0) red[w] = ssum;
    __syncthreads();
    float mu = (red[0] + red[1]) * (1.f / 128.f);
    float dv = a - mu;
    float qq = dv * dv;
#pragma unroll
    for (int o = 1; o < 64; o <<= 1) qq += __shfl_xor(qq, o);
    __syncthreads();
    if (lane == 0) red[w] = qq;
    __syncthreads();
    float var = (red[0] + red[1]) * (1.f / 128.f);
    float v = dv * rsqrtf(var + 1e-5f) * lng[d] + lnb[d];
    v = fmaxf(v, 0.f);
    t1[d] = v;
    __syncthreads();
    float o2 = b2[d];
    for (int k = 0; k < 128; ++k) o2 += t1[k] * W2[k * 128 + d];
    out[g * 128 + d] = o2;
}

extern "C" void kernel_launch(void* const* d_in, const int* in_sizes, int n_in,
                              void* d_out, int out_size, void* d_ws, size_t ws_size,
                              hipStream_t stream) {
    const float* x    = (const float*)d_in[0];
    const int*   edge = (const int*)d_in[1];
    const int*   src  = edge;
    const int*   dst  = edge + NEDGES;
    const int*   batch = (const int*)d_in[2];
    const float* nW   = (const float*)d_in[3];
    const float* nb   = (const float*)d_in[4];
    const float* W1s  = (const float*)d_in[5];
    const float* b1s  = (const float*)d_in[6];
    const float* W2s  = (const float*)d_in[7];
    const float* b2s  = (const float*)d_in[8];
    const float* bng  = (const float*)d_in[9];
    const float* bnb  = (const float*)d_in[10];
    const float* vne  = (const float*)d_in[11];
    const float* vW1  = (const float*)d_in[12];
    const float* vb1  = (const float*)d_in[13];
    const float* vW2  = (const float*)d_in[14];
    const float* vb2  = (const float*)d_in[15];
    const float* gW1  = (const float*)d_in[16];
    const float* gb1  = (const float*)d_in[17];
    const float* lng  = (const float*)d_in[18];
    const float* lnb  = (const float*)d_in[19];
    const float* gW2  = (const float*)d_in[20];
    const float* gb2  = (const float*)d_in[21];

    char* ws = (char*)d_ws;
    auto alloc = [&](size_t bytes) { char* p = ws; ws += (bytes + 255) & ~(size_t)255; return p; };
    float*  stats = (float*)alloc((size_t)NSTAT * 256 * 4);    // 32 copies of colsum+colsq
    ushort* hb    = (ushort*)alloc((size_t)NPAD * 128 * 2);    // h in bf16
    ushort* mbuf  = (ushort*)alloc((size_t)NPAD * 128 * 2);
    ushort* xb    = (ushort*)alloc((size_t)NPAD * 128 * 2);
    float*  vn    = (float*)alloc((size_t)NGRAPH * 128 * 4);
    ushort* w1t   = (ushort*)alloc((size_t)NLAYER * 256 * 128 * 2);
    ushort* w2t   = (ushort*)alloc((size_t)NLAYER * 128 * 256 * 2);
    float*  inv   = (float*)alloc((size_t)NGRAPH * 4);
    int*    gstart= (int*)alloc((size_t)(NGRAPH + 1) * 4);
    int*    deg   = (int*)alloc((size_t)NNODES * 4);
    int*    rs    = (int*)alloc((size_t)(NNODES + 1) * 4);
    int*    cursor= (int*)alloc((size_t)NNODES * 4);
    int*    csrc  = (int*)alloc((size_t)NEDGES * 4);
    int*    partials = (int*)alloc((size_t)SCAN_NB * 4);

    float* outN = (float*)d_out;
    float* outG = outN + (size_t)NNODES * 128;

    hipMemsetAsync(stats, 0, (size_t)NSTAT * 256 * 4, stream);
    hipMemsetAsync(deg, 0, (size_t)NNODES * 4, stream);

    // CSR build (edges constant across layers)
    deg_kernel<<<(NEDGES + 255) / 256, 256, 0, stream>>>(dst, deg);
    scan_part_kernel<<<SCAN_NB, 256, 0, stream>>>(deg, partials);
    scan_top_kernel<<<1, 512, 0, stream>>>(partials);
    scan_blocks_kernel<<<SCAN_NB, 256, 0, stream>>>(deg, partials, rs, cursor);
    csr_scatter_kernel<<<(NEDGES + 255) / 256, 256, 0, stream>>>(src, dst, cursor, csrc);
    gstart_kernel<<<(NGRAPH + 256) / 256, 256, 0, stream>>>(batch, gstart, inv);

    prep_w_kernel<<<(2 * NLAYER * 128 * 256 + 255) / 256, 256, 0, stream>>>(W1s, W2s, w1t, w2t);
    node_embed_kernel<<<((NNODES + NGRAPH) * 128 + 255) / 256, 256, 0, stream>>>(
        x, nW, nb, hb, vne, vn);

    const int flatNB = (NNODES * 16 + 511) / 512;   // 3125
    for (int i = 0; i < NLAYER; ++i) {
        gin_agg_kernel<<<(NNODES + 15) / 16, 256, 0, stream>>>(hb, rs, csrc, xb);
        fused_mlp_kernel<<<MLP_GRID, 256, 0, stream>>>(
            xb, w1t + (size_t)i * 256 * 128, b1s + i * 256,
            w2t + (size_t)i * 128 * 256, b2s + i * 128, mbuf, stats);
        bn_apply_kernel<<<flatNB, 512, 0, stream>>>(
            mbuf, stats, bng + i * 128, bnb + i * 128, hb, i > 0 ? 1 : 0);
        vn_update_kernel<<<NGRAPH, 128, 0, stream>>>(hb, gstart, inv, vW1, vb1, vW2, vb2, vn, stats);
        if (i < NLAYER - 1)
            add_vn_kernel<0><<<flatNB, 512, 0, stream>>>(hb, vn, batch, nullptr);
        else
            add_vn_kernel<1><<<flatNB, 512, 0, stream>>>(hb, vn, batch, outN);
    }
    graph_mlp_kernel<<<NGRAPH, 128, 0, stream>>>(hb, gstart, inv, vn, gW1, gb1, lng, lnb, gW2, gb2, outG);
}